// Round 1
// baseline (7368.011 us; speedup 1.0000x reference)
//
#include <hip/hip_runtime.h>
#include <math.h>

#define D   256
#define E   4
#define H   8
#define LYR 8
#define PCH 4
#define IMG 128
#define BB  8
#define NC  10
#define T   1024
#define NPER 256
#define DH  32
#define D4  1024
#define TT_MLP 8

// ---------------- prep: batched transpose  dst[l][c][r] = src[l][r][c] ----------------
__global__ void transpose_b(const float* __restrict__ src, float* __restrict__ dst,
                            int Lb, int R, int C) {
    long idx = (long)blockIdx.x * blockDim.x + threadIdx.x;
    long total = (long)Lb * R * C;
    if (idx >= total) return;
    int c = (int)(idx % C);
    long rem = idx / C;
    int r = (int)(rem % R);
    int l = (int)(rem / R);
    dst[((long)l * C + c) * R + r] = src[idx];
}

// ---------------- patch embed + pos emb ----------------
__global__ void patch_embed(const float* __restrict__ x, const float* __restrict__ pw,
                            const float* __restrict__ pb, const float* __restrict__ pos,
                            float* __restrict__ tok) {
    int t = blockIdx.x, b = blockIdx.y, d = threadIdx.x;
    __shared__ float sx[48];
    int ph = t >> 5, pwc = t & 31;
    if (d < 48) {
        int c = d >> 4, ij = d & 15, i = ij >> 2, j = ij & 3;
        sx[d] = x[(((long)b * 3 + c) * IMG + (ph * 4 + i)) * IMG + (pwc * 4 + j)];
    }
    __syncthreads();
    float acc = pb[d];
    #pragma unroll
    for (int kk = 0; kk < 48; ++kk) acc += sx[kk] * pw[d * 48 + kk];
    tok[((long)b * T + t) * D + d] = acc + pos[(long)t * D + d];
}

// ---------------- router: logits + softmax over E=4 ----------------
__global__ void router(const float* __restrict__ tok, const float* __restrict__ rw,
                       const float* __restrict__ rb, float* __restrict__ rawp) {
    int row = blockIdx.x;          // b*T + t
    int lane = threadIdx.x;        // 64
    const float* tr = tok + (long)row * D;
    float a0 = 0.f, a1 = 0.f, a2 = 0.f, a3 = 0.f;
    for (int c = lane; c < D; c += 64) {
        float xv = tr[c];
        a0 += xv * rw[0 * D + c];
        a1 += xv * rw[1 * D + c];
        a2 += xv * rw[2 * D + c];
        a3 += xv * rw[3 * D + c];
    }
    for (int off = 32; off; off >>= 1) {
        a0 += __shfl_down(a0, off);
        a1 += __shfl_down(a1, off);
        a2 += __shfl_down(a2, off);
        a3 += __shfl_down(a3, off);
    }
    if (lane == 0) {
        float l0 = a0 + rb[0], l1 = a1 + rb[1], l2 = a2 + rb[2], l3 = a3 + rb[3];
        float mx = fmaxf(fmaxf(l0, l1), fmaxf(l2, l3));
        float e0 = __expf(l0 - mx), e1 = __expf(l1 - mx), e2 = __expf(l2 - mx), e3 = __expf(l3 - mx);
        float inv = 1.0f / (e0 + e1 + e2 + e3);
        rawp[(long)row * 4 + 0] = e0 * inv;
        rawp[(long)row * 4 + 1] = e1 * inv;
        rawp[(long)row * 4 + 2] = e2 * inv;
        rawp[(long)row * 4 + 3] = e3 * inv;
    }
}

// ---------------- greedy iterative top-k routing (partition only) ----------------
__global__ __launch_bounds__(1024) void route_topk(const float* __restrict__ rawp,
                                                   int* __restrict__ perm,
                                                   float* __restrict__ rpsel) {
    int b = blockIdx.x, tid = threadIdx.x;
    __shared__ float sv[T];
    __shared__ int   si[T];
    __shared__ int   assigned[T];
    assigned[tid] = 0;
    __syncthreads();
    for (int e = 0; e < E; ++e) {
        float val = assigned[tid] ? -3.4e38f : rawp[((long)b * T + tid) * E + e];
        sv[tid] = val; si[tid] = tid;
        __syncthreads();
        // bitonic sort, descending by value, ascending index tiebreak
        for (int k = 2; k <= T; k <<= 1) {
            for (int j = k >> 1; j > 0; j >>= 1) {
                int ixj = tid ^ j;
                if (ixj > tid) {
                    float v1 = sv[tid], v2 = sv[ixj];
                    int i1 = si[tid], i2 = si[ixj];
                    // "tid elem should come AFTER ixj elem" in descending order
                    bool after = (v1 < v2) || (v1 == v2 && i1 > i2);
                    bool dir = ((tid & k) == 0);
                    if (after == dir) {
                        sv[tid] = v2; sv[ixj] = v1;
                        si[tid] = i2; si[ixj] = i1;
                    }
                }
                __syncthreads();
            }
        }
        if (tid < NPER) {
            int orig = si[tid];
            perm[(long)b * T + e * NPER + tid] = orig;
            rpsel[(long)b * T + e * NPER + tid] = rawp[((long)b * T + orig) * E + e];
        }
        __syncthreads();
        if (tid < NPER) assigned[si[tid]] = 1;
        __syncthreads();
    }
}

// ---------------- gather tokens into routed order ----------------
__global__ void gather_tokens(const float* __restrict__ tok, const int* __restrict__ perm,
                              float* __restrict__ xs) {
    int slot = blockIdx.x, b = blockIdx.y, d = threadIdx.x;
    int src = perm[(long)b * T + slot];
    xs[((long)b * T + slot) * D + d] = tok[((long)b * T + src) * D + d];
}

// ---------------- layernorm over D ----------------
__global__ void layernorm(const float* __restrict__ in, float* __restrict__ out,
                          const float* __restrict__ g, const float* __restrict__ bta) {
    int row = blockIdx.x;
    int tid = threadIdx.x;
    float v = in[(long)row * D + tid];
    __shared__ float red[4];
    float s = v;
    for (int off = 32; off; off >>= 1) s += __shfl_down(s, off);
    if ((tid & 63) == 0) red[tid >> 6] = s;
    __syncthreads();
    float mu = (red[0] + red[1] + red[2] + red[3]) * (1.0f / D);
    float dv = v - mu;
    float s2 = dv * dv;
    for (int off = 32; off; off >>= 1) s2 += __shfl_down(s2, off);
    __syncthreads();
    if ((tid & 63) == 0) red[tid >> 6] = s2;
    __syncthreads();
    float var = (red[0] + red[1] + red[2] + red[3]) * (1.0f / D);
    out[(long)row * D + tid] = dv * rsqrtf(var + 1e-5f) * g[tid] + bta[tid];
}

// ---------------- fused q/k/v projection, 32-token tile ----------------
__global__ __launch_bounds__(256) void qkv_proj(
    const float* __restrict__ xn,
    const float* __restrict__ wqT, const float* __restrict__ wkT, const float* __restrict__ wvT,
    const float* __restrict__ bq, const float* __restrict__ bk, const float* __restrict__ bv,
    float* __restrict__ q, float* __restrict__ k, float* __restrict__ v) {
    int tile = blockIdx.x, b = blockIdx.y, d = threadIdx.x;
    int slot0 = tile * 32;
    int m = D >> (slot0 >> 8);
    __shared__ float sx[32 * D];
    long base = ((long)b * T + slot0) * D;
    #pragma unroll
    for (int tt = 0; tt < 32; ++tt) sx[tt * D + d] = xn[base + tt * D + d];
    __syncthreads();
    float aq[32], ak[32], av[32];
    #pragma unroll
    for (int tt = 0; tt < 32; ++tt) { aq[tt] = 0.f; ak[tt] = 0.f; av[tt] = 0.f; }
    for (int c = 0; c < m; c += 4) {
        const float* pq = wqT + (long)c * D + d;
        const float* pk = wkT + (long)c * D + d;
        const float* pv = wvT + (long)c * D + d;
        float q0 = pq[0], q1 = pq[D], q2 = pq[2 * D], q3 = pq[3 * D];
        float k0 = pk[0], k1 = pk[D], k2 = pk[2 * D], k3 = pk[3 * D];
        float v0 = pv[0], v1 = pv[D], v2 = pv[2 * D], v3 = pv[3 * D];
        #pragma unroll
        for (int tt = 0; tt < 32; ++tt) {
            float4 xv = *(const float4*)&sx[tt * D + c];
            aq[tt] += xv.x * q0 + xv.y * q1 + xv.z * q2 + xv.w * q3;
            ak[tt] += xv.x * k0 + xv.y * k1 + xv.z * k2 + xv.w * k3;
            av[tt] += xv.x * v0 + xv.y * v1 + xv.z * v2 + xv.w * v3;
        }
    }
    float cq = bq[d], ck = bk[d], cv = bv[d];
    #pragma unroll
    for (int tt = 0; tt < 32; ++tt) {
        q[base + tt * D + d] = aq[tt] + cq;
        k[base + tt * D + d] = ak[tt] + ck;
        v[base + tt * D + d] = av[tt] + cv;
    }
}

// ---------------- attention: one query per thread, K/V via wave-uniform global reads
// no-max softmax (logits bounded; exact same result as softmax in fp32) ----------------
__global__ __launch_bounds__(256) void attention(
    const float* __restrict__ q, const float* __restrict__ k,
    const float* __restrict__ v, float* __restrict__ ao) {
    int qt = blockIdx.x, h = blockIdx.y, b = blockIdx.z;
    int tid = threadIdx.x;
    int qslot = qt * 256 + tid;
    long qbase = ((long)b * T + qslot) * D + h * DH;
    float qr[DH];
    #pragma unroll
    for (int i = 0; i < DH; ++i) qr[i] = q[qbase + i] * 0.0625f;   // fold scale = D^-0.5
    float acc[DH];
    #pragma unroll
    for (int i = 0; i < DH; ++i) acc[i] = 0.f;
    float lsum = 0.f;
    const float* kb_ = k + ((long)b * T) * D + h * DH;
    const float* vb_ = v + ((long)b * T) * D + h * DH;
    #pragma unroll 4
    for (int kk = 0; kk < T; ++kk) {
        const float4* kr = (const float4*)(kb_ + (long)kk * D);
        float s0 = 0.f, s1 = 0.f, s2 = 0.f, s3 = 0.f;
        #pragma unroll
        for (int i = 0; i < 8; ++i) {
            float4 kv = kr[i];
            s0 += qr[4 * i + 0] * kv.x;
            s1 += qr[4 * i + 1] * kv.y;
            s2 += qr[4 * i + 2] * kv.z;
            s3 += qr[4 * i + 3] * kv.w;
        }
        float p = __expf((s0 + s1) + (s2 + s3));
        lsum += p;
        const float4* vr = (const float4*)(vb_ + (long)kk * D);
        #pragma unroll
        for (int i = 0; i < 8; ++i) {
            float4 vv = vr[i];
            acc[4 * i + 0] += p * vv.x;
            acc[4 * i + 1] += p * vv.y;
            acc[4 * i + 2] += p * vv.z;
            acc[4 * i + 3] += p * vv.w;
        }
    }
    float inv = 1.0f / lsum;
    #pragma unroll
    for (int i = 0; i < DH; ++i) ao[qbase + i] = acc[i] * inv;
}

// ---------------- O projection (m x m) + residual ----------------
__global__ __launch_bounds__(256) void oproj_residual(
    const float* __restrict__ ao, const float* __restrict__ woT,
    const float* __restrict__ bo, float* __restrict__ xs) {
    int tile = blockIdx.x, b = blockIdx.y, d = threadIdx.x;
    int slot0 = tile * 32;
    int m = D >> (slot0 >> 8);
    __shared__ float sa[32 * D];
    long base = ((long)b * T + slot0) * D;
    #pragma unroll
    for (int tt = 0; tt < 32; ++tt) sa[tt * D + d] = ao[base + tt * D + d];
    __syncthreads();
    if (d >= m) return;   // padded dims: residual unchanged
    float acc[32];
    #pragma unroll
    for (int tt = 0; tt < 32; ++tt) acc[tt] = 0.f;
    for (int c = 0; c < m; c += 4) {
        const float* pw = woT + (long)c * D + d;
        float w0 = pw[0], w1 = pw[D], w2 = pw[2 * D], w3 = pw[3 * D];
        #pragma unroll
        for (int tt = 0; tt < 32; ++tt) {
            float4 xv = *(const float4*)&sa[tt * D + c];
            acc[tt] += xv.x * w0 + xv.y * w1 + xv.z * w2 + xv.w * w3;
        }
    }
    float bb = bo[d];
    #pragma unroll
    for (int tt = 0; tt < 32; ++tt)
        xs[base + tt * D + d] += acc[tt] + bb;
}

// ---------------- fused MLP: l1 + exact gelu + l2 + scale-factor residual ----------------
__global__ __launch_bounds__(256) void mlp_fused(
    const float* __restrict__ xn, const float* __restrict__ w1T, const float* __restrict__ b1,
    const float* __restrict__ w2T, const float* __restrict__ b2,
    const float* __restrict__ rpsel, const float* __restrict__ alpha,
    float* __restrict__ xs) {
    int tile = blockIdx.x, b = blockIdx.y, tid = threadIdx.x;
    int slot0 = tile * TT_MLP;
    int m = D >> (slot0 >> 8);
    __shared__ float sx[TT_MLP * D];
    __shared__ float si[TT_MLP * D4];
    long base = ((long)b * T + slot0) * D;
    #pragma unroll
    for (int tt = 0; tt < TT_MLP; ++tt) sx[tt * D + tid] = xn[base + tt * D + tid];
    __syncthreads();
    // phase 1: inner = gelu(xn[:, :m] @ w1[:, :m].T + b1)
    float acc[4][TT_MLP];
    #pragma unroll
    for (int fc = 0; fc < 4; ++fc)
        #pragma unroll
        for (int tt = 0; tt < TT_MLP; ++tt) acc[fc][tt] = 0.f;
    for (int c = 0; c < m; c += 4) {
        float4 xv[TT_MLP];
        #pragma unroll
        for (int tt = 0; tt < TT_MLP; ++tt) xv[tt] = *(const float4*)&sx[tt * D + c];
        #pragma unroll
        for (int fc = 0; fc < 4; ++fc) {
            const float* wp = w1T + (long)c * D4 + fc * 256 + tid;
            float w0 = wp[0], w1 = wp[D4], w2 = wp[2 * D4], w3 = wp[3 * D4];
            #pragma unroll
            for (int tt = 0; tt < TT_MLP; ++tt)
                acc[fc][tt] += xv[tt].x * w0 + xv[tt].y * w1 + xv[tt].z * w2 + xv[tt].w * w3;
        }
    }
    #pragma unroll
    for (int fc = 0; fc < 4; ++fc) {
        int f = fc * 256 + tid;
        float bb = b1[f];
        #pragma unroll
        for (int tt = 0; tt < TT_MLP; ++tt) {
            float xv = acc[fc][tt] + bb;
            si[tt * D4 + f] = 0.5f * xv * (1.0f + erff(xv * 0.70710678118654752f));
        }
    }
    __syncthreads();
    // phase 2: outer = inner @ w2[:m, :].T + b2 ; xs += sf * outer (d < m only)
    int d = tid;
    if (d < m) {
        float acc2[TT_MLP];
        #pragma unroll
        for (int tt = 0; tt < TT_MLP; ++tt) acc2[tt] = 0.f;
        for (int f = 0; f < D4; f += 4) {
            const float* wp = w2T + (long)f * D + d;
            float w0 = wp[0], w1 = wp[D], w2 = wp[2 * D], w3 = wp[3 * D];
            #pragma unroll
            for (int tt = 0; tt < TT_MLP; ++tt) {
                float4 iv = *(const float4*)&si[tt * D4 + f];
                acc2[tt] += iv.x * w0 + iv.y * w1 + iv.z * w2 + iv.w * w3;
            }
        }
        float bb = b2[d];
        float a1 = alpha[0];
        #pragma unroll
        for (int tt = 0; tt < TT_MLP; ++tt) {
            float sf = a1 * rpsel[(long)b * T + slot0 + tt] + 1.0f;
            xs[base + tt * D + d] += sf * (acc2[tt] + bb);
        }
    }
}

// ---------------- mean pool + classification head ----------------
__global__ void head_out(const float* __restrict__ xs, const float* __restrict__ hw,
                         const float* __restrict__ hb, float* __restrict__ out) {
    int b = blockIdx.x, d = threadIdx.x;
    __shared__ float smean[D];
    float s = 0.f;
    for (int slot = 0; slot < T; ++slot) s += xs[((long)b * T + slot) * D + d];
    smean[d] = s * (1.0f / T);
    __syncthreads();
    if (d < NC) {
        float acc = hb[d];
        for (int c = 0; c < D; ++c) acc += smean[c] * hw[d * D + c];
        out[b * NC + d] = acc;
    }
}

extern "C" void kernel_launch(void* const* d_in, const int* in_sizes, int n_in,
                              void* d_out, int out_size, void* d_ws, size_t ws_size,
                              hipStream_t stream) {
    const float* x      = (const float*)d_in[0];
    const float* patchw = (const float*)d_in[1];
    const float* patchb = (const float*)d_in[2];
    const float* pos    = (const float*)d_in[3];
    const float* rw     = (const float*)d_in[4];
    const float* rb     = (const float*)d_in[5];
    const float* ln1g   = (const float*)d_in[6];
    const float* ln1b   = (const float*)d_in[7];
    const float* qw     = (const float*)d_in[8];
    const float* qbi    = (const float*)d_in[9];
    const float* kw     = (const float*)d_in[10];
    const float* kbi    = (const float*)d_in[11];
    const float* vw     = (const float*)d_in[12];
    const float* vbi    = (const float*)d_in[13];
    const float* ow     = (const float*)d_in[14];
    const float* obi    = (const float*)d_in[15];
    const float* ln2g   = (const float*)d_in[16];
    const float* ln2b   = (const float*)d_in[17];
    const float* l1w    = (const float*)d_in[18];
    const float* l1b    = (const float*)d_in[19];
    const float* l2w    = (const float*)d_in[20];
    const float* l2b    = (const float*)d_in[21];
    const float* hw     = (const float*)d_in[22];
    const float* hb     = (const float*)d_in[23];
    const float* alpha  = (const float*)d_in[24];

    float* ws = (float*)d_ws;
    const long NTD = (long)BB * T * D;
    float* tok   = ws;              // also reused as ao after gather
    float* xs    = tok + NTD;
    float* xn    = xs + NTD;
    float* bufQ  = xn + NTD;
    float* bufK  = bufQ + NTD;
    float* bufV  = bufK + NTD;
    float* rawp  = bufV + NTD;                       // B*T*E
    float* rpsel = rawp + (long)BB * T * E;          // B*T
    int*   perm  = (int*)(rpsel + (long)BB * T);     // B*T ints
    float* qT    = (float*)(perm + (long)BB * T);
    float* kT    = qT + (long)LYR * D * D;
    float* vT    = kT + (long)LYR * D * D;
    float* oT    = vT + (long)LYR * D * D;
    float* w1T   = oT + (long)LYR * D * D;           // L * D * D4  ([c][f])
    float* w2T   = w1T + (long)LYR * D * D4;         // L * D4 * D  ([f][d])
    float* ao    = tok;                              // alias: tok dead after gather

    {
        long n1 = (long)LYR * D * D;
        int g1 = (int)((n1 + 255) / 256);
        transpose_b<<<g1, 256, 0, stream>>>(qw, qT, LYR, D, D);
        transpose_b<<<g1, 256, 0, stream>>>(kw, kT, LYR, D, D);
        transpose_b<<<g1, 256, 0, stream>>>(vw, vT, LYR, D, D);
        transpose_b<<<g1, 256, 0, stream>>>(ow, oT, LYR, D, D);
        long n2 = (long)LYR * D4 * D;
        int g2 = (int)((n2 + 255) / 256);
        transpose_b<<<g2, 256, 0, stream>>>(l1w, w1T, LYR, D4, D);
        transpose_b<<<g2, 256, 0, stream>>>(l2w, w2T, LYR, D, D4);
    }

    patch_embed<<<dim3(T, BB), D, 0, stream>>>(x, patchw, patchb, pos, tok);
    router<<<BB * T, 64, 0, stream>>>(tok, rw, rb, rawp);
    route_topk<<<BB, 1024, 0, stream>>>(rawp, perm, rpsel);
    gather_tokens<<<dim3(T, BB), D, 0, stream>>>(tok, perm, xs);

    for (int l = 0; l < LYR; ++l) {
        layernorm<<<BB * T, D, 0, stream>>>(xs, xn, ln1g + l * D, ln1b + l * D);
        qkv_proj<<<dim3(T / 32, BB), 256, 0, stream>>>(
            xn, qT + (long)l * D * D, kT + (long)l * D * D, vT + (long)l * D * D,
            qbi + l * D, kbi + l * D, vbi + l * D, bufQ, bufK, bufV);
        attention<<<dim3(T / 256, H, BB), 256, 0, stream>>>(bufQ, bufK, bufV, ao);
        oproj_residual<<<dim3(T / 32, BB), 256, 0, stream>>>(
            ao, oT + (long)l * D * D, obi + l * D, xs);
        layernorm<<<BB * T, D, 0, stream>>>(xs, xn, ln2g + l * D, ln2b + l * D);
        mlp_fused<<<dim3(T / TT_MLP, BB), 256, 0, stream>>>(
            xn, w1T + (long)l * D * D4, l1b + (long)l * D4,
            w2T + (long)l * D4 * D, l2b + l * D, rpsel, alpha, xs);
    }

    head_out<<<BB, D, 0, stream>>>(xs, hw, hb, (float*)d_out);
}

// Round 2
// 1426.447 us; speedup vs baseline: 5.1653x; 5.1653x over previous
//
#include <hip/hip_runtime.h>
#include <math.h>

#define D 256
#define E 4
#define H 8
#define LYR 8
#define IMG 128
#define BB 8
#define NC 10
#define T 1024
#define NPER 256
#define DH 32
#define D4 1024

using bf16x8 = __attribute__((ext_vector_type(8))) __bf16;
using bf16x4 = __attribute__((ext_vector_type(4))) __bf16;
using f32x4  = __attribute__((ext_vector_type(4))) float;

#define MFMA16(a, b, c) __builtin_amdgcn_mfma_f32_16x16x32_bf16((a), (b), (c), 0, 0, 0)

// ---------------- cast f32 -> bf16 (vectorized x4) ----------------
__global__ void cast_bf16_k(const float* __restrict__ src, __bf16* __restrict__ dst, long n4) {
    long i = (long)blockIdx.x * blockDim.x + threadIdx.x;
    if (i >= n4) return;
    float4 v = ((const float4*)src)[i];
    bf16x4 o;
    o[0] = (__bf16)v.x; o[1] = (__bf16)v.y; o[2] = (__bf16)v.z; o[3] = (__bf16)v.w;
    ((bf16x4*)dst)[i] = o;
}

// ---------------- patch embed + pos emb (fp32, exact) ----------------
__global__ void patch_embed(const float* __restrict__ x, const float* __restrict__ pw,
                            const float* __restrict__ pb, const float* __restrict__ pos,
                            float* __restrict__ tok) {
    int t = blockIdx.x, b = blockIdx.y, d = threadIdx.x;
    __shared__ float sx[48];
    int ph = t >> 5, pwc = t & 31;
    if (d < 48) {
        int c = d >> 4, ij = d & 15, i = ij >> 2, j = ij & 3;
        sx[d] = x[(((long)b * 3 + c) * IMG + (ph * 4 + i)) * IMG + (pwc * 4 + j)];
    }
    __syncthreads();
    float acc = pb[d];
    #pragma unroll
    for (int kk = 0; kk < 48; ++kk) acc += sx[kk] * pw[d * 48 + kk];
    tok[((long)b * T + t) * D + d] = acc + pos[(long)t * D + d];
}

// ---------------- router softmax (fp32, exact) ----------------
__global__ void router(const float* __restrict__ tok, const float* __restrict__ rw,
                       const float* __restrict__ rb, float* __restrict__ rawp) {
    int row = blockIdx.x;
    int lane = threadIdx.x;
    const float* tr = tok + (long)row * D;
    float a0 = 0.f, a1 = 0.f, a2 = 0.f, a3 = 0.f;
    for (int c = lane; c < D; c += 64) {
        float xv = tr[c];
        a0 += xv * rw[0 * D + c];
        a1 += xv * rw[1 * D + c];
        a2 += xv * rw[2 * D + c];
        a3 += xv * rw[3 * D + c];
    }
    for (int off = 32; off; off >>= 1) {
        a0 += __shfl_down(a0, off);
        a1 += __shfl_down(a1, off);
        a2 += __shfl_down(a2, off);
        a3 += __shfl_down(a3, off);
    }
    if (lane == 0) {
        float l0 = a0 + rb[0], l1 = a1 + rb[1], l2 = a2 + rb[2], l3 = a3 + rb[3];
        float mx = fmaxf(fmaxf(l0, l1), fmaxf(l2, l3));
        float e0 = __expf(l0 - mx), e1 = __expf(l1 - mx), e2 = __expf(l2 - mx), e3 = __expf(l3 - mx);
        float inv = 1.0f / (e0 + e1 + e2 + e3);
        rawp[(long)row * 4 + 0] = e0 * inv;
        rawp[(long)row * 4 + 1] = e1 * inv;
        rawp[(long)row * 4 + 2] = e2 * inv;
        rawp[(long)row * 4 + 3] = e3 * inv;
    }
}

// ---------------- greedy iterative top-k routing (fp32, exact partition) ----------------
__global__ __launch_bounds__(1024) void route_topk(const float* __restrict__ rawp,
                                                   int* __restrict__ perm,
                                                   float* __restrict__ rpsel) {
    int b = blockIdx.x, tid = threadIdx.x;
    __shared__ float sv[T];
    __shared__ int   si[T];
    __shared__ int   assigned[T];
    assigned[tid] = 0;
    __syncthreads();
    for (int e = 0; e < E; ++e) {
        float val = assigned[tid] ? -3.4e38f : rawp[((long)b * T + tid) * E + e];
        sv[tid] = val; si[tid] = tid;
        __syncthreads();
        for (int k = 2; k <= T; k <<= 1) {
            for (int j = k >> 1; j > 0; j >>= 1) {
                int ixj = tid ^ j;
                if (ixj > tid) {
                    float v1 = sv[tid], v2 = sv[ixj];
                    int i1 = si[tid], i2 = si[ixj];
                    bool after = (v1 < v2) || (v1 == v2 && i1 > i2);
                    bool dir = ((tid & k) == 0);
                    if (after == dir) {
                        sv[tid] = v2; sv[ixj] = v1;
                        si[tid] = i2; si[ixj] = i1;
                    }
                }
                __syncthreads();
            }
        }
        if (tid < NPER) {
            int orig = si[tid];
            perm[(long)b * T + e * NPER + tid] = orig;
            rpsel[(long)b * T + e * NPER + tid] = rawp[((long)b * T + orig) * E + e];
        }
        __syncthreads();
        if (tid < NPER) assigned[si[tid]] = 1;
        __syncthreads();
    }
}

// ---------------- gather tokens into routed order (fp32) ----------------
__global__ void gather_tokens(const float* __restrict__ tok, const int* __restrict__ perm,
                              float* __restrict__ xs) {
    int slot = blockIdx.x, b = blockIdx.y, d = threadIdx.x;
    int src = perm[(long)b * T + slot];
    xs[((long)b * T + slot) * D + d] = tok[((long)b * T + src) * D + d];
}

// ---------------- layernorm (fp32 math, bf16 output for MFMA A-operands) ----------------
__global__ void layernorm_bf16(const float* __restrict__ in, __bf16* __restrict__ out,
                               const float* __restrict__ g, const float* __restrict__ bta) {
    int row = blockIdx.x;
    int tid = threadIdx.x;
    float v = in[(long)row * D + tid];
    __shared__ float red[4];
    float s = v;
    for (int off = 32; off; off >>= 1) s += __shfl_down(s, off);
    if ((tid & 63) == 0) red[tid >> 6] = s;
    __syncthreads();
    float mu = (red[0] + red[1] + red[2] + red[3]) * (1.0f / D);
    float dv = v - mu;
    float s2 = dv * dv;
    for (int off = 32; off; off >>= 1) s2 += __shfl_down(s2, off);
    __syncthreads();
    if ((tid & 63) == 0) red[tid >> 6] = s2;
    __syncthreads();
    float var = (red[0] + red[1] + red[2] + red[3]) * (1.0f / D);
    out[(long)row * D + tid] = (__bf16)(dv * rsqrtf(var + 1e-5f) * g[tid] + bta[tid]);
}

// ---------------- MFMA GEMM core: wave computes 32x64 tile, K-loop step 32 ----------------
// A: [rows][K] row-major bf16 (activations). W: [cols][K] row-major bf16 (native weights).
// A-frag: lane reads A[lr][lk..lk+8); B-frag: lane reads W[n0+lr][lk..lk+8) — both 16B loads.
// C/D layout (measured, m89): col = lane&15, row = (lane>>4)*4 + r.
__device__ __forceinline__ void gemm_tile(
    const __bf16* __restrict__ A, int lda,
    const __bf16* __restrict__ W, int ldb,
    int K, int lane, f32x4 acc[2][4])
{
    int lr = lane & 15, lk = (lane >> 4) * 8;
    const __bf16* a0 = A + (long)lr * lda + lk;
    const __bf16* a1 = a0 + 16 * lda;
    const __bf16* b0 = W + (long)lr * ldb + lk;
    const __bf16* b1 = b0 + 16 * ldb;
    const __bf16* b2 = b0 + 32 * ldb;
    const __bf16* b3 = b0 + 48 * ldb;
    #pragma unroll 2
    for (int k = 0; k < K; k += 32) {
        bf16x8 av0 = *(const bf16x8*)(a0 + k);
        bf16x8 av1 = *(const bf16x8*)(a1 + k);
        bf16x8 bv0 = *(const bf16x8*)(b0 + k);
        bf16x8 bv1 = *(const bf16x8*)(b1 + k);
        bf16x8 bv2 = *(const bf16x8*)(b2 + k);
        bf16x8 bv3 = *(const bf16x8*)(b3 + k);
        acc[0][0] = MFMA16(av0, bv0, acc[0][0]);
        acc[0][1] = MFMA16(av0, bv1, acc[0][1]);
        acc[0][2] = MFMA16(av0, bv2, acc[0][2]);
        acc[0][3] = MFMA16(av0, bv3, acc[0][3]);
        acc[1][0] = MFMA16(av1, bv0, acc[1][0]);
        acc[1][1] = MFMA16(av1, bv1, acc[1][1]);
        acc[1][2] = MFMA16(av1, bv2, acc[1][2]);
        acc[1][3] = MFMA16(av1, bv3, acc[1][3]);
    }
}

#define GEMM_PROLOGUE \
    int lane = threadIdx.x & 63, wid = threadIdx.x >> 6; \
    int wm = wid >> 1, wn = wid & 1; \
    int b = blockIdx.z >> 2, e = blockIdx.z & 3; \
    int m = D >> e; \
    const f32x4 vz = {0.f, 0.f, 0.f, 0.f}; \
    f32x4 acc[2][4]; \
    _Pragma("unroll") \
    for (int i = 0; i < 2; ++i) { acc[i][0]=vz; acc[i][1]=vz; acc[i][2]=vz; acc[i][3]=vz; }

// ---------------- QKV projection GEMM; writes bf16 Q,K row-major + V transposed ----------------
__global__ __launch_bounds__(256) void qkv_gemm(
    const __bf16* __restrict__ xnb,
    const __bf16* __restrict__ qwb, const __bf16* __restrict__ kwb, const __bf16* __restrict__ vwb,
    const float* __restrict__ qb, const float* __restrict__ kb, const float* __restrict__ vb,
    __bf16* __restrict__ Qb, __bf16* __restrict__ Kb, __bf16* __restrict__ Vt)
{
    GEMM_PROLOGUE
    int which = blockIdx.y >> 1;                 // 0=q 1=k 2=v (128-col blocks never straddle)
    int ncol0 = (blockIdx.y & 1) * 128 + wn * 64;
    int row0 = e * NPER + blockIdx.x * 64 + wm * 32;
    const __bf16* W = which == 0 ? qwb : which == 1 ? kwb : vwb;
    const float* bias = which == 0 ? qb : which == 1 ? kb : vb;
    gemm_tile(xnb + ((long)b * T + row0) * D, D, W + (long)ncol0 * D, D, m, lane, acc);
    int lr = lane & 15, rg = (lane >> 4) * 4;
    #pragma unroll
    for (int i = 0; i < 2; ++i) {
        int row = row0 + i * 16 + rg;
        #pragma unroll
        for (int j = 0; j < 4; ++j) {
            int n = ncol0 + j * 16 + lr;
            float bv = bias[n];
            if (which == 2) {
                bf16x4 pk;
                #pragma unroll
                for (int r = 0; r < 4; ++r) pk[r] = (__bf16)(acc[i][j][r] + bv);
                *(bf16x4*)&Vt[((long)b * D + n) * T + row] = pk;
            } else if (which == 0) {
                #pragma unroll
                for (int r = 0; r < 4; ++r)   // fold attention scale 2^-4 into Q
                    Qb[((long)b * T + row + r) * D + n] = (__bf16)((acc[i][j][r] + bv) * 0.0625f);
            } else {
                #pragma unroll
                for (int r = 0; r < 4; ++r)
                    Kb[((long)b * T + row + r) * D + n] = (__bf16)(acc[i][j][r] + bv);
            }
        }
    }
}

// ---------------- attention: MFMA flash, 16 queries/wave, no-max softmax ----------------
__global__ __launch_bounds__(256) void attn_mfma(
    const __bf16* __restrict__ Qb, const __bf16* __restrict__ Kb,
    const __bf16* __restrict__ Vt, __bf16* __restrict__ aob)
{
    int tid = threadIdx.x;
    int lane = tid & 63, wave = tid >> 6;
    int h = blockIdx.y, b = blockIdx.z;
    int q0 = blockIdx.x * 64 + wave * 16;
    int lr = lane & 15, lk8 = (lane >> 4) * 8;
    __shared__ __bf16 plds[4][16][32];   // wave-private P transpose buffers — no barriers
    const f32x4 vz = {0.f, 0.f, 0.f, 0.f};
    bf16x8 qf = *(const bf16x8*)&Qb[((long)b * T + q0 + lr) * D + h * DH + lk8];
    f32x4 acc0 = vz, acc1 = vz;
    float ls0 = 0.f, ls1 = 0.f, ls2 = 0.f, ls3 = 0.f;
    const __bf16* kbase = Kb + ((long)b * T) * D + h * DH + lk8;
    const __bf16* vbase = Vt + ((long)b * D + h * DH) * T;
    int prow = (lane >> 4) * 4;
    for (int kc = 0; kc < T; kc += 32) {
        bf16x8 kf0 = *(const bf16x8*)(kbase + (long)(kc + lr) * D);
        bf16x8 kf1 = *(const bf16x8*)(kbase + (long)(kc + 16 + lr) * D);
        f32x4 s0 = MFMA16(qf, kf0, vz);
        f32x4 s1 = MFMA16(qf, kf1, vz);
        float p0[4], p1[4];
        #pragma unroll
        for (int r = 0; r < 4; ++r) { p0[r] = __expf(s0[r]); p1[r] = __expf(s1[r]); }
        ls0 += p0[0] + p1[0]; ls1 += p0[1] + p1[1];
        ls2 += p0[2] + p1[2]; ls3 += p0[3] + p1[3];
        #pragma unroll
        for (int r = 0; r < 4; ++r) {
            plds[wave][prow + r][lr]      = (__bf16)p0[r];
            plds[wave][prow + r][16 + lr] = (__bf16)p1[r];
        }
        bf16x8 pa  = *(const bf16x8*)&plds[wave][lr][lk8];
        bf16x8 vf0 = *(const bf16x8*)(vbase + (long)lr * T + kc + lk8);
        bf16x8 vf1 = *(const bf16x8*)(vbase + (long)(16 + lr) * T + kc + lk8);
        acc0 = MFMA16(pa, vf0, acc0);
        acc1 = MFMA16(pa, vf1, acc1);
    }
    #pragma unroll
    for (int mk = 1; mk < 16; mk <<= 1) {
        ls0 += __shfl_xor(ls0, mk); ls1 += __shfl_xor(ls1, mk);
        ls2 += __shfl_xor(ls2, mk); ls3 += __shfl_xor(ls3, mk);
    }
    float inv[4] = {1.f / ls0, 1.f / ls1, 1.f / ls2, 1.f / ls3};
    long obase = ((long)b * T + q0 + prow) * D + h * DH;
    #pragma unroll
    for (int r = 0; r < 4; ++r) {
        aob[obase + (long)r * D + lr]      = (__bf16)(acc0[r] * inv[r]);
        aob[obase + (long)r * D + 16 + lr] = (__bf16)(acc1[r] * inv[r]);
    }
}

// ---------------- O projection GEMM + residual into fp32 xs ----------------
__global__ __launch_bounds__(256) void oproj_gemm(
    const __bf16* __restrict__ aob, const __bf16* __restrict__ owb,
    const float* __restrict__ ob, float* __restrict__ xs)
{
    GEMM_PROLOGUE
    if ((int)blockIdx.y * 128 >= m) return;
    int ncol0 = blockIdx.y * 128 + wn * 64;
    int row0 = e * NPER + blockIdx.x * 64 + wm * 32;
    gemm_tile(aob + ((long)b * T + row0) * D, D, owb + (long)ncol0 * D, D, m, lane, acc);
    int lr = lane & 15, rg = (lane >> 4) * 4;
    #pragma unroll
    for (int i = 0; i < 2; ++i) {
        int row = row0 + i * 16 + rg;
        #pragma unroll
        for (int j = 0; j < 4; ++j) {
            int n = ncol0 + j * 16 + lr;
            if (n < m) {
                float bv = ob[n];
                #pragma unroll
                for (int r = 0; r < 4; ++r)
                    xs[((long)b * T + row + r) * D + n] += acc[i][j][r] + bv;
            }
        }
    }
}

// ---------------- MLP layer 1 GEMM + exact gelu -> bf16 inner ----------------
__global__ __launch_bounds__(256) void mlp1_gemm(
    const __bf16* __restrict__ xnb, const __bf16* __restrict__ w1b,
    const float* __restrict__ b1, __bf16* __restrict__ innerb)
{
    GEMM_PROLOGUE
    int ncol0 = blockIdx.y * 128 + wn * 64;
    int row0 = e * NPER + blockIdx.x * 64 + wm * 32;
    gemm_tile(xnb + ((long)b * T + row0) * D, D, w1b + (long)ncol0 * D, D, m, lane, acc);
    int lr = lane & 15, rg = (lane >> 4) * 4;
    #pragma unroll
    for (int i = 0; i < 2; ++i) {
        int row = row0 + i * 16 + rg;
        #pragma unroll
        for (int j = 0; j < 4; ++j) {
            int f = ncol0 + j * 16 + lr;
            float bv = b1[f];
            #pragma unroll
            for (int r = 0; r < 4; ++r) {
                float xv = acc[i][j][r] + bv;
                float gl = 0.5f * xv * (1.0f + erff(xv * 0.70710678118654752f));
                innerb[((long)b * T + row + r) * D4 + f] = (__bf16)gl;
            }
        }
    }
}

// ---------------- MLP layer 2 GEMM + sf-scaled residual into fp32 xs ----------------
__global__ __launch_bounds__(256) void mlp2_gemm(
    const __bf16* __restrict__ innerb, const __bf16* __restrict__ w2b,
    const float* __restrict__ b2, const float* __restrict__ rpsel,
    const float* __restrict__ alpha, float* __restrict__ xs)
{
    GEMM_PROLOGUE
    if ((int)blockIdx.y * 128 >= m) return;
    int ncol0 = blockIdx.y * 128 + wn * 64;
    int row0 = e * NPER + blockIdx.x * 64 + wm * 32;
    gemm_tile(innerb + ((long)b * T + row0) * D4, D4, w2b + (long)ncol0 * D4, D4, D4, lane, acc);
    int lr = lane & 15, rg = (lane >> 4) * 4;
    float a0 = alpha[0];
    #pragma unroll
    for (int i = 0; i < 2; ++i) {
        int row = row0 + i * 16 + rg;
        float sf[4];
        #pragma unroll
        for (int r = 0; r < 4; ++r) sf[r] = a0 * rpsel[(long)b * T + row + r] + 1.0f;
        #pragma unroll
        for (int j = 0; j < 4; ++j) {
            int n = ncol0 + j * 16 + lr;
            if (n < m) {
                float bv = b2[n];
                #pragma unroll
                for (int r = 0; r < 4; ++r)
                    xs[((long)b * T + row + r) * D + n] += sf[r] * (acc[i][j][r] + bv);
            }
        }
    }
}

// ---------------- mean pool + head (fp32) ----------------
__global__ void head_out(const float* __restrict__ xs, const float* __restrict__ hw,
                         const float* __restrict__ hb, float* __restrict__ out) {
    int b = blockIdx.x, d = threadIdx.x;
    __shared__ float smean[D];
    float s = 0.f;
    for (int slot = 0; slot < T; ++slot) s += xs[((long)b * T + slot) * D + d];
    smean[d] = s * (1.0f / T);
    __syncthreads();
    if (d < NC) {
        float acc = hb[d];
        for (int c = 0; c < D; ++c) acc += smean[c] * hw[d * D + c];
        out[b * NC + d] = acc;
    }
}

extern "C" void kernel_launch(void* const* d_in, const int* in_sizes, int n_in,
                              void* d_out, int out_size, void* d_ws, size_t ws_size,
                              hipStream_t stream) {
    const float* x      = (const float*)d_in[0];
    const float* patchw = (const float*)d_in[1];
    const float* patchb = (const float*)d_in[2];
    const float* pos    = (const float*)d_in[3];
    const float* rw     = (const float*)d_in[4];
    const float* rb     = (const float*)d_in[5];
    const float* ln1g   = (const float*)d_in[6];
    const float* ln1b   = (const float*)d_in[7];
    const float* qw     = (const float*)d_in[8];
    const float* qbi    = (const float*)d_in[9];
    const float* kw     = (const float*)d_in[10];
    const float* kbi    = (const float*)d_in[11];
    const float* vw     = (const float*)d_in[12];
    const float* vbi    = (const float*)d_in[13];
    const float* ow     = (const float*)d_in[14];
    const float* obi    = (const float*)d_in[15];
    const float* ln2g   = (const float*)d_in[16];
    const float* ln2b   = (const float*)d_in[17];
    const float* l1w    = (const float*)d_in[18];
    const float* l1b    = (const float*)d_in[19];
    const float* l2w    = (const float*)d_in[20];
    const float* l2b    = (const float*)d_in[21];
    const float* hw     = (const float*)d_in[22];
    const float* hb     = (const float*)d_in[23];
    const float* alpha  = (const float*)d_in[24];

    char* p = (char*)d_ws;
    auto alloc = [&](size_t bytes) { void* r = (void*)p; p += (bytes + 255) & ~(size_t)255; return r; };
    const long NTD = (long)BB * T * D;

    float*  tok    = (float*)alloc(NTD * 4);
    float*  xs     = (float*)alloc(NTD * 4);
    float*  rawp   = (float*)alloc((long)BB * T * E * 4);
    float*  rpsel  = (float*)alloc((long)BB * T * 4);
    int*    perm   = (int*)alloc((long)BB * T * 4);
    __bf16* xnb    = (__bf16*)alloc(NTD * 2);
    __bf16* Qb     = (__bf16*)alloc(NTD * 2);
    __bf16* Kb     = (__bf16*)alloc(NTD * 2);
    __bf16* Vt     = (__bf16*)alloc(NTD * 2);
    __bf16* aob    = (__bf16*)alloc(NTD * 2);
    __bf16* innerb = (__bf16*)alloc((long)BB * T * D4 * 2);
    __bf16* qwb    = (__bf16*)alloc((long)LYR * D * D * 2);
    __bf16* kwb    = (__bf16*)alloc((long)LYR * D * D * 2);
    __bf16* vwb    = (__bf16*)alloc((long)LYR * D * D * 2);
    __bf16* owb    = (__bf16*)alloc((long)LYR * D * D * 2);
    __bf16* w1b    = (__bf16*)alloc((long)LYR * D4 * D * 2);
    __bf16* w2b    = (__bf16*)alloc((long)LYR * D * D4 * 2);

    auto cast = [&](const float* s, __bf16* d, long n) {
        long n4 = n / 4;
        cast_bf16_k<<<(int)((n4 + 255) / 256), 256, 0, stream>>>(s, d, n4);
    };
    cast(qw, qwb, (long)LYR * D * D);
    cast(kw, kwb, (long)LYR * D * D);
    cast(vw, vwb, (long)LYR * D * D);
    cast(ow, owb, (long)LYR * D * D);
    cast(l1w, w1b, (long)LYR * D4 * D);
    cast(l2w, w2b, (long)LYR * D * D4);

    patch_embed<<<dim3(T, BB), D, 0, stream>>>(x, patchw, patchb, pos, tok);
    router<<<BB * T, 64, 0, stream>>>(tok, rw, rb, rawp);
    route_topk<<<BB, 1024, 0, stream>>>(rawp, perm, rpsel);
    gather_tokens<<<dim3(T, BB), D, 0, stream>>>(tok, perm, xs);

    for (int l = 0; l < LYR; ++l) {
        layernorm_bf16<<<BB * T, D, 0, stream>>>(xs, xnb, ln1g + l * D, ln1b + l * D);
        qkv_gemm<<<dim3(4, 6, BB * E), 256, 0, stream>>>(
            xnb, qwb + (long)l * D * D, kwb + (long)l * D * D, vwb + (long)l * D * D,
            qbi + l * D, kbi + l * D, vbi + l * D, Qb, Kb, Vt);
        attn_mfma<<<dim3(T / 64, H, BB), 256, 0, stream>>>(Qb, Kb, Vt, aob);
        oproj_gemm<<<dim3(4, 2, BB * E), 256, 0, stream>>>(
            aob, owb + (long)l * D * D, obi + l * D, xs);
        layernorm_bf16<<<BB * T, D, 0, stream>>>(xs, xnb, ln2g + l * D, ln2b + l * D);
        mlp1_gemm<<<dim3(4, 8, BB * E), 256, 0, stream>>>(
            xnb, w1b + (long)l * D4 * D, l1b + (long)l * D4, innerb);
        mlp2_gemm<<<dim3(4, 2, BB * E), 256, 0, stream>>>(
            innerb, w2b + (long)l * D * D4, l2b + l * D, rpsel, alpha, xs);
    }

    head_out<<<BB, D, 0, stream>>>(xs, hw, hb, (float*)d_out);
}

// Round 3
// 1163.586 us; speedup vs baseline: 6.3322x; 1.2259x over previous
//
#include <hip/hip_runtime.h>
#include <math.h>

#define D 256
#define E 4
#define H 8
#define LYR 8
#define IMG 128
#define BB 8
#define NC 10
#define T 1024
#define NPER 256
#define DH 32
#define D4 1024

using bf16x8 = __attribute__((ext_vector_type(8))) __bf16;
using bf16x4 = __attribute__((ext_vector_type(4))) __bf16;
using f32x4  = __attribute__((ext_vector_type(4))) float;

#define MFMA16(a, b, c) __builtin_amdgcn_mfma_f32_16x16x32_bf16((a), (b), (c), 0, 0, 0)

// ---------------- cast f32 -> bf16 (vectorized x4) ----------------
__global__ void cast_bf16_k(const float* __restrict__ src, __bf16* __restrict__ dst, long n4) {
    long i = (long)blockIdx.x * blockDim.x + threadIdx.x;
    if (i >= n4) return;
    float4 v = ((const float4*)src)[i];
    bf16x4 o;
    o[0] = (__bf16)v.x; o[1] = (__bf16)v.y; o[2] = (__bf16)v.z; o[3] = (__bf16)v.w;
    ((bf16x4*)dst)[i] = o;
}

// ---------------- patch embed + pos emb (fp32, exact: feeds discrete routing) ----------------
__global__ void patch_embed(const float* __restrict__ x, const float* __restrict__ pw,
                            const float* __restrict__ pb, const float* __restrict__ pos,
                            float* __restrict__ tok) {
    int t = blockIdx.x, b = blockIdx.y, d = threadIdx.x;
    __shared__ float sx[48];
    int ph = t >> 5, pwc = t & 31;
    if (d < 48) {
        int c = d >> 4, ij = d & 15, i = ij >> 2, j = ij & 3;
        sx[d] = x[(((long)b * 3 + c) * IMG + (ph * 4 + i)) * IMG + (pwc * 4 + j)];
    }
    __syncthreads();
    float acc = pb[d];
    #pragma unroll
    for (int kk = 0; kk < 48; ++kk) acc += sx[kk] * pw[d * 48 + kk];
    tok[((long)b * T + t) * D + d] = acc + pos[(long)t * D + d];
}

// ---------------- router softmax (fp32, exact) ----------------
__global__ void router(const float* __restrict__ tok, const float* __restrict__ rw,
                       const float* __restrict__ rb, float* __restrict__ rawp) {
    int row = blockIdx.x;
    int lane = threadIdx.x;
    const float* tr = tok + (long)row * D;
    float a0 = 0.f, a1 = 0.f, a2 = 0.f, a3 = 0.f;
    for (int c = lane; c < D; c += 64) {
        float xv = tr[c];
        a0 += xv * rw[0 * D + c];
        a1 += xv * rw[1 * D + c];
        a2 += xv * rw[2 * D + c];
        a3 += xv * rw[3 * D + c];
    }
    for (int off = 32; off; off >>= 1) {
        a0 += __shfl_down(a0, off);
        a1 += __shfl_down(a1, off);
        a2 += __shfl_down(a2, off);
        a3 += __shfl_down(a3, off);
    }
    if (lane == 0) {
        float l0 = a0 + rb[0], l1 = a1 + rb[1], l2 = a2 + rb[2], l3 = a3 + rb[3];
        float mx = fmaxf(fmaxf(l0, l1), fmaxf(l2, l3));
        float e0 = __expf(l0 - mx), e1 = __expf(l1 - mx), e2 = __expf(l2 - mx), e3 = __expf(l3 - mx);
        float inv = 1.0f / (e0 + e1 + e2 + e3);
        rawp[(long)row * 4 + 0] = e0 * inv;
        rawp[(long)row * 4 + 1] = e1 * inv;
        rawp[(long)row * 4 + 2] = e2 * inv;
        rawp[(long)row * 4 + 3] = e3 * inv;
    }
}

// ---------------- greedy iterative top-k routing (fp32, exact partition) ----------------
__global__ __launch_bounds__(1024) void route_topk(const float* __restrict__ rawp,
                                                   int* __restrict__ perm,
                                                   float* __restrict__ rpsel) {
    int b = blockIdx.x, tid = threadIdx.x;
    __shared__ float sv[T];
    __shared__ int   si[T];
    __shared__ int   assigned[T];
    assigned[tid] = 0;
    __syncthreads();
    for (int e = 0; e < E; ++e) {
        float val = assigned[tid] ? -3.4e38f : rawp[((long)b * T + tid) * E + e];
        sv[tid] = val; si[tid] = tid;
        __syncthreads();
        for (int k = 2; k <= T; k <<= 1) {
            for (int j = k >> 1; j > 0; j >>= 1) {
                int ixj = tid ^ j;
                if (ixj > tid) {
                    float v1 = sv[tid], v2 = sv[ixj];
                    int i1 = si[tid], i2 = si[ixj];
                    bool after = (v1 < v2) || (v1 == v2 && i1 > i2);
                    bool dir = ((tid & k) == 0);
                    if (after == dir) {
                        sv[tid] = v2; sv[ixj] = v1;
                        si[tid] = i2; si[ixj] = i1;
                    }
                }
                __syncthreads();
            }
        }
        if (tid < NPER) {
            int orig = si[tid];
            perm[(long)b * T + e * NPER + tid] = orig;
            rpsel[(long)b * T + e * NPER + tid] = rawp[((long)b * T + orig) * E + e];
        }
        __syncthreads();
        if (tid < NPER) assigned[si[tid]] = 1;
        __syncthreads();
    }
}

// ---------------- gather tokens into routed order (fp32) ----------------
__global__ void gather_tokens(const float* __restrict__ tok, const int* __restrict__ perm,
                              float* __restrict__ xs) {
    int slot = blockIdx.x, b = blockIdx.y, d = threadIdx.x;
    int src = perm[(long)b * T + slot];
    xs[((long)b * T + slot) * D + d] = tok[((long)b * T + src) * D + d];
}

// ---------------- layernorm: one row per WAVE, shuffle-only, no barriers ----------------
__global__ __launch_bounds__(256) void layernorm_bf16(const float* __restrict__ in,
                                                      __bf16* __restrict__ out,
                                                      const float* __restrict__ g,
                                                      const float* __restrict__ bta) {
    int lane = threadIdx.x & 63, wave = threadIdx.x >> 6;
    long row = (long)blockIdx.x * 4 + wave;
    float4 v = *(const float4*)&in[row * D + lane * 4];
    float s = (v.x + v.y) + (v.z + v.w);
    #pragma unroll
    for (int m = 1; m < 64; m <<= 1) s += __shfl_xor(s, m);
    float mu = s * (1.0f / D);
    float d0 = v.x - mu, d1 = v.y - mu, d2 = v.z - mu, d3 = v.w - mu;
    float s2 = (d0 * d0 + d1 * d1) + (d2 * d2 + d3 * d3);
    #pragma unroll
    for (int m = 1; m < 64; m <<= 1) s2 += __shfl_xor(s2, m);
    float rstd = rsqrtf(s2 * (1.0f / D) + 1e-5f);
    float4 gv = *(const float4*)&g[lane * 4];
    float4 bv = *(const float4*)&bta[lane * 4];
    bf16x4 o;
    o[0] = (__bf16)(d0 * rstd * gv.x + bv.x);
    o[1] = (__bf16)(d1 * rstd * gv.y + bv.y);
    o[2] = (__bf16)(d2 * rstd * gv.z + bv.z);
    o[3] = (__bf16)(d3 * rstd * gv.w + bv.w);
    *(bf16x4*)&out[row * D + lane * 4] = o;
}

// ---------------- MFMA GEMM core: wave computes 32x64 tile, K-loop step 32 ----------------
__device__ __forceinline__ void gemm_tile(
    const __bf16* __restrict__ A, int lda,
    const __bf16* __restrict__ W, int ldb,
    int K, int lane, f32x4 acc[2][4])
{
    int lr = lane & 15, lk = (lane >> 4) * 8;
    const __bf16* a0 = A + (long)lr * lda + lk;
    const __bf16* a1 = a0 + 16 * lda;
    const __bf16* b0 = W + (long)lr * ldb + lk;
    const __bf16* b1 = b0 + 16 * ldb;
    const __bf16* b2 = b0 + 32 * ldb;
    const __bf16* b3 = b0 + 48 * ldb;
    #pragma unroll 2
    for (int k = 0; k < K; k += 32) {
        bf16x8 av0 = *(const bf16x8*)(a0 + k);
        bf16x8 av1 = *(const bf16x8*)(a1 + k);
        bf16x8 bv0 = *(const bf16x8*)(b0 + k);
        bf16x8 bv1 = *(const bf16x8*)(b1 + k);
        bf16x8 bv2 = *(const bf16x8*)(b2 + k);
        bf16x8 bv3 = *(const bf16x8*)(b3 + k);
        acc[0][0] = MFMA16(av0, bv0, acc[0][0]);
        acc[0][1] = MFMA16(av0, bv1, acc[0][1]);
        acc[0][2] = MFMA16(av0, bv2, acc[0][2]);
        acc[0][3] = MFMA16(av0, bv3, acc[0][3]);
        acc[1][0] = MFMA16(av1, bv0, acc[1][0]);
        acc[1][1] = MFMA16(av1, bv1, acc[1][1]);
        acc[1][2] = MFMA16(av1, bv2, acc[1][2]);
        acc[1][3] = MFMA16(av1, bv3, acc[1][3]);
    }
}

#define GEMM_PROLOGUE \
    int lane = threadIdx.x & 63, wid = threadIdx.x >> 6; \
    int wm = wid >> 1, wn = wid & 1; \
    int b = blockIdx.z >> 2, e = blockIdx.z & 3; \
    int m = D >> e; \
    const f32x4 vz = {0.f, 0.f, 0.f, 0.f}; \
    f32x4 acc[2][4]; \
    _Pragma("unroll") \
    for (int i = 0; i < 2; ++i) { acc[i][0]=vz; acc[i][1]=vz; acc[i][2]=vz; acc[i][3]=vz; }

// ---------------- QKV projection GEMM; writes bf16 Q,K row-major + V transposed ----------------
__global__ __launch_bounds__(256) void qkv_gemm(
    const __bf16* __restrict__ xnb,
    const __bf16* __restrict__ qwb, const __bf16* __restrict__ kwb, const __bf16* __restrict__ vwb,
    const float* __restrict__ qb, const float* __restrict__ kb, const float* __restrict__ vb,
    __bf16* __restrict__ Qb, __bf16* __restrict__ Kb, __bf16* __restrict__ Vt)
{
    GEMM_PROLOGUE
    int which = blockIdx.y >> 1;
    int ncol0 = (blockIdx.y & 1) * 128 + wn * 64;
    int row0 = e * NPER + blockIdx.x * 64 + wm * 32;
    const __bf16* W = which == 0 ? qwb : which == 1 ? kwb : vwb;
    const float* bias = which == 0 ? qb : which == 1 ? kb : vb;
    gemm_tile(xnb + ((long)b * T + row0) * D, D, W + (long)ncol0 * D, D, m, lane, acc);
    int lr = lane & 15, rg = (lane >> 4) * 4;
    #pragma unroll
    for (int i = 0; i < 2; ++i) {
        int row = row0 + i * 16 + rg;
        #pragma unroll
        for (int j = 0; j < 4; ++j) {
            int n = ncol0 + j * 16 + lr;
            float bv = bias[n];
            if (which == 2) {
                bf16x4 pk;
                #pragma unroll
                for (int r = 0; r < 4; ++r) pk[r] = (__bf16)(acc[i][j][r] + bv);
                *(bf16x4*)&Vt[((long)b * D + n) * T + row] = pk;
            } else if (which == 0) {
                #pragma unroll
                for (int r = 0; r < 4; ++r)   // fold attention scale 2^-4 into Q
                    Qb[((long)b * T + row + r) * D + n] = (__bf16)((acc[i][j][r] + bv) * 0.0625f);
            } else {
                #pragma unroll
                for (int r = 0; r < 4; ++r)
                    Kb[((long)b * T + row + r) * D + n] = (__bf16)(acc[i][j][r] + bv);
            }
        }
    }
}

// ---------------- attention: swapped-QK^T MFMA flash, 32 q/wave, KVBLK=64, no barriers ------
// S^T = mfma(K,Q): lane (g,lr) holds 4 consecutive KEYS (4g..4g+3) of query lr
//   -> packed b64 LDS write, stride-72 rows => bank-optimal writes AND b128 reads.
// Grid: 1D 512, swizzled so all 8 q-blocks of one (b,h) share an XCD (L2 locality).
__global__ __launch_bounds__(256) void attn_mfma(
    const __bf16* __restrict__ Qb, const __bf16* __restrict__ Kb,
    const __bf16* __restrict__ Vt, __bf16* __restrict__ aob)
{
    int bid = blockIdx.x;
    int bh = (bid & 7) * 8 + ((bid >> 3) & 7);
    int qt = bid >> 6;
    int b = bh >> 3, h = bh & 7;
    int lane = threadIdx.x & 63, wave = threadIdx.x >> 6;
    int lr = lane & 15, g = lane >> 4;
    int q0 = qt * 128 + wave * 32;
    __shared__ __bf16 plds[4][32][72];
    const f32x4 vz = {0.f, 0.f, 0.f, 0.f};
    bf16x8 qf[2];
    qf[0] = *(const bf16x8*)&Qb[((long)b * T + q0 + lr) * D + h * DH + g * 8];
    qf[1] = *(const bf16x8*)&Qb[((long)b * T + q0 + 16 + lr) * D + h * DH + g * 8];
    f32x4 acc[2][2] = {{vz, vz}, {vz, vz}};
    float ls[2] = {0.f, 0.f};
    const __bf16* kbase = Kb + (long)b * T * D + h * DH + g * 8;
    const __bf16* vbase = Vt + ((long)b * D + h * DH) * T;
    for (int kc = 0; kc < T; kc += 64) {
        bf16x8 kf[4];
        #pragma unroll
        for (int j = 0; j < 4; ++j)
            kf[j] = *(const bf16x8*)(kbase + (long)(kc + 16 * j + lr) * D);
        bf16x8 vf[2][2];
        #pragma unroll
        for (int w = 0; w < 2; ++w)
            #pragma unroll
            for (int df = 0; df < 2; ++df)
                vf[w][df] = *(const bf16x8*)(vbase + (long)(df * 16 + lr) * T + kc + 32 * w + 8 * g);
        #pragma unroll
        for (int qi = 0; qi < 2; ++qi) {
            #pragma unroll
            for (int j = 0; j < 4; ++j) {
                f32x4 s = MFMA16(kf[j], qf[qi], vz);   // S^T tile: rows=keys, cols=queries
                float p0 = __expf(s[0]), p1 = __expf(s[1]);
                float p2 = __expf(s[2]), p3 = __expf(s[3]);
                ls[qi] += (p0 + p1) + (p2 + p3);
                bf16x4 pk;
                pk[0] = (__bf16)p0; pk[1] = (__bf16)p1;
                pk[2] = (__bf16)p2; pk[3] = (__bf16)p3;
                *(bf16x4*)&plds[wave][qi * 16 + lr][16 * j + 4 * g] = pk;
            }
        }
        #pragma unroll
        for (int qi = 0; qi < 2; ++qi) {
            #pragma unroll
            for (int w = 0; w < 2; ++w) {
                bf16x8 pa = *(const bf16x8*)&plds[wave][qi * 16 + lr][32 * w + 8 * g];
                acc[qi][0] = MFMA16(pa, vf[w][0], acc[qi][0]);
                acc[qi][1] = MFMA16(pa, vf[w][1], acc[qi][1]);
            }
        }
    }
    #pragma unroll
    for (int qi = 0; qi < 2; ++qi) {
        ls[qi] += __shfl_xor(ls[qi], 16);
        ls[qi] += __shfl_xor(ls[qi], 32);
        float inv = 1.0f / ls[qi];
        #pragma unroll
        for (int r = 0; r < 4; ++r) {
            float invr = __shfl(inv, 4 * g + r);   // sum for query 4g+r lives at lane lr==4g+r
            long obase = ((long)b * T + q0 + qi * 16 + 4 * g + r) * D + h * DH;
            aob[obase + lr]      = (__bf16)(acc[qi][0][r] * invr);
            aob[obase + 16 + lr] = (__bf16)(acc[qi][1][r] * invr);
        }
    }
}

// ---------------- O projection GEMM + residual into fp32 xs ----------------
__global__ __launch_bounds__(256) void oproj_gemm(
    const __bf16* __restrict__ aob, const __bf16* __restrict__ owb,
    const float* __restrict__ ob, float* __restrict__ xs)
{
    GEMM_PROLOGUE
    if ((int)blockIdx.y * 128 >= m) return;
    int ncol0 = blockIdx.y * 128 + wn * 64;
    int row0 = e * NPER + blockIdx.x * 64 + wm * 32;
    gemm_tile(aob + ((long)b * T + row0) * D, D, owb + (long)ncol0 * D, D, m, lane, acc);
    int lr = lane & 15, rg = (lane >> 4) * 4;
    #pragma unroll
    for (int i = 0; i < 2; ++i) {
        int row = row0 + i * 16 + rg;
        #pragma unroll
        for (int j = 0; j < 4; ++j) {
            int n = ncol0 + j * 16 + lr;
            if (n < m) {
                float bv = ob[n];
                #pragma unroll
                for (int r = 0; r < 4; ++r)
                    xs[((long)b * T + row + r) * D + n] += acc[i][j][r] + bv;
            }
        }
    }
}

// ---------------- MLP layer 1 GEMM + exact gelu -> bf16 inner ----------------
__global__ __launch_bounds__(256) void mlp1_gemm(
    const __bf16* __restrict__ xnb, const __bf16* __restrict__ w1b,
    const float* __restrict__ b1, __bf16* __restrict__ innerb)
{
    GEMM_PROLOGUE
    int ncol0 = blockIdx.y * 128 + wn * 64;
    int row0 = e * NPER + blockIdx.x * 64 + wm * 32;
    gemm_tile(xnb + ((long)b * T + row0) * D, D, w1b + (long)ncol0 * D, D, m, lane, acc);
    int lr = lane & 15, rg = (lane >> 4) * 4;
    #pragma unroll
    for (int i = 0; i < 2; ++i) {
        int row = row0 + i * 16 + rg;
        #pragma unroll
        for (int j = 0; j < 4; ++j) {
            int f = ncol0 + j * 16 + lr;
            float bv = b1[f];
            #pragma unroll
            for (int r = 0; r < 4; ++r) {
                float xv = acc[i][j][r] + bv;
                float gl = 0.5f * xv * (1.0f + erff(xv * 0.70710678118654752f));
                innerb[((long)b * T + row + r) * D4 + f] = (__bf16)gl;
            }
        }
    }
}

// ---------------- MLP layer 2 GEMM + sf-scaled residual into fp32 xs ----------------
__global__ __launch_bounds__(256) void mlp2_gemm(
    const __bf16* __restrict__ innerb, const __bf16* __restrict__ w2b,
    const float* __restrict__ b2, const float* __restrict__ rpsel,
    const float* __restrict__ alpha, float* __restrict__ xs)
{
    GEMM_PROLOGUE
    if ((int)blockIdx.y * 128 >= m) return;
    int ncol0 = blockIdx.y * 128 + wn * 64;
    int row0 = e * NPER + blockIdx.x * 64 + wm * 32;
    gemm_tile(innerb + ((long)b * T + row0) * D4, D4, w2b + (long)ncol0 * D4, D4, D4, lane, acc);
    int lr = lane & 15, rg = (lane >> 4) * 4;
    float a0 = alpha[0];
    #pragma unroll
    for (int i = 0; i < 2; ++i) {
        int row = row0 + i * 16 + rg;
        float sf[4];
        #pragma unroll
        for (int r = 0; r < 4; ++r) sf[r] = a0 * rpsel[(long)b * T + row + r] + 1.0f;
        #pragma unroll
        for (int j = 0; j < 4; ++j) {
            int n = ncol0 + j * 16 + lr;
            if (n < m) {
                float bv = b2[n];
                #pragma unroll
                for (int r = 0; r < 4; ++r)
                    xs[((long)b * T + row + r) * D + n] += sf[r] * (acc[i][j][r] + bv);
            }
        }
    }
}

// ---------------- mean pool + head (fp32) ----------------
__global__ void head_out(const float* __restrict__ xs, const float* __restrict__ hw,
                         const float* __restrict__ hb, float* __restrict__ out) {
    int b = blockIdx.x, d = threadIdx.x;
    __shared__ float smean[D];
    float s = 0.f;
    for (int slot = 0; slot < T; ++slot) s += xs[((long)b * T + slot) * D + d];
    smean[d] = s * (1.0f / T);
    __syncthreads();
    if (d < NC) {
        float acc = hb[d];
        for (int c = 0; c < D; ++c) acc += smean[c] * hw[d * D + c];
        out[b * NC + d] = acc;
    }
}

extern "C" void kernel_launch(void* const* d_in, const int* in_sizes, int n_in,
                              void* d_out, int out_size, void* d_ws, size_t ws_size,
                              hipStream_t stream) {
    const float* x      = (const float*)d_in[0];
    const float* patchw = (const float*)d_in[1];
    const float* patchb = (const float*)d_in[2];
    const float* pos    = (const float*)d_in[3];
    const float* rw     = (const float*)d_in[4];
    const float* rb     = (const float*)d_in[5];
    const float* ln1g   = (const float*)d_in[6];
    const float* ln1b   = (const float*)d_in[7];
    const float* qw     = (const float*)d_in[8];
    const float* qbi    = (const float*)d_in[9];
    const float* kw     = (const float*)d_in[10];
    const float* kbi    = (const float*)d_in[11];
    const float* vw     = (const float*)d_in[12];
    const float* vbi    = (const float*)d_in[13];
    const float* ow     = (const float*)d_in[14];
    const float* obi    = (const float*)d_in[15];
    const float* ln2g   = (const float*)d_in[16];
    const float* ln2b   = (const float*)d_in[17];
    const float* l1w    = (const float*)d_in[18];
    const float* l1b    = (const float*)d_in[19];
    const float* l2w    = (const float*)d_in[20];
    const float* l2b    = (const float*)d_in[21];
    const float* hw     = (const float*)d_in[22];
    const float* hb     = (const float*)d_in[23];
    const float* alpha  = (const float*)d_in[24];

    char* p = (char*)d_ws;
    auto alloc = [&](size_t bytes) { void* r = (void*)p; p += (bytes + 255) & ~(size_t)255; return r; };
    const long NTD = (long)BB * T * D;

    float*  tok    = (float*)alloc(NTD * 4);
    float*  xs     = (float*)alloc(NTD * 4);
    float*  rawp   = (float*)alloc((long)BB * T * E * 4);
    float*  rpsel  = (float*)alloc((long)BB * T * 4);
    int*    perm   = (int*)alloc((long)BB * T * 4);
    __bf16* xnb    = (__bf16*)alloc(NTD * 2);
    __bf16* Qb     = (__bf16*)alloc(NTD * 2);
    __bf16* Kb     = (__bf16*)alloc(NTD * 2);
    __bf16* Vt     = (__bf16*)alloc(NTD * 2);
    __bf16* aob    = (__bf16*)alloc(NTD * 2);
    __bf16* innerb = (__bf16*)alloc((long)BB * T * D4 * 2);
    __bf16* qwb    = (__bf16*)alloc((long)LYR * D * D * 2);
    __bf16* kwb    = (__bf16*)alloc((long)LYR * D * D * 2);
    __bf16* vwb    = (__bf16*)alloc((long)LYR * D * D * 2);
    __bf16* owb    = (__bf16*)alloc((long)LYR * D * D * 2);
    __bf16* w1b    = (__bf16*)alloc((long)LYR * D4 * D * 2);
    __bf16* w2b    = (__bf16*)alloc((long)LYR * D * D4 * 2);

    auto cast = [&](const float* s, __bf16* d, long n) {
        long n4 = n / 4;
        cast_bf16_k<<<(int)((n4 + 255) / 256), 256, 0, stream>>>(s, d, n4);
    };
    cast(qw, qwb, (long)LYR * D * D);
    cast(kw, kwb, (long)LYR * D * D);
    cast(vw, vwb, (long)LYR * D * D);
    cast(ow, owb, (long)LYR * D * D);
    cast(l1w, w1b, (long)LYR * D4 * D);
    cast(l2w, w2b, (long)LYR * D * D4);

    patch_embed<<<dim3(T, BB), D, 0, stream>>>(x, patchw, patchb, pos, tok);
    router<<<BB * T, 64, 0, stream>>>(tok, rw, rb, rawp);
    route_topk<<<BB, 1024, 0, stream>>>(rawp, perm, rpsel);
    gather_tokens<<<dim3(T, BB), D, 0, stream>>>(tok, perm, xs);

    for (int l = 0; l < LYR; ++l) {
        layernorm_bf16<<<BB * T / 4, 256, 0, stream>>>(xs, xnb, ln1g + l * D, ln1b + l * D);
        qkv_gemm<<<dim3(4, 6, BB * E), 256, 0, stream>>>(
            xnb, qwb + (long)l * D * D, kwb + (long)l * D * D, vwb + (long)l * D * D,
            qbi + l * D, kbi + l * D, vbi + l * D, Qb, Kb, Vt);
        attn_mfma<<<dim3(512), 256, 0, stream>>>(Qb, Kb, Vt, aob);
        oproj_gemm<<<dim3(4, 2, BB * E), 256, 0, stream>>>(
            aob, owb + (long)l * D * D, obi + l * D, xs);
        layernorm_bf16<<<BB * T / 4, 256, 0, stream>>>(xs, xnb, ln2g + l * D, ln2b + l * D);
        mlp1_gemm<<<dim3(4, 8, BB * E), 256, 0, stream>>>(
            xnb, w1b + (long)l * D4 * D, l1b + (long)l * D4, innerb);
        mlp2_gemm<<<dim3(4, 2, BB * E), 256, 0, stream>>>(
            innerb, w2b + (long)l * D * D4, l2b + l * D, rpsel, alpha, xs);
    }

    head_out<<<BB, D, 0, stream>>>(xs, hw, hb, (float*)d_out);
}

// Round 4
// 1035.850 us; speedup vs baseline: 7.1130x; 1.1233x over previous
//
#include <hip/hip_runtime.h>
#include <math.h>

#define D 256
#define E 4
#define H 8
#define LYR 8
#define IMG 128
#define BB 8
#define NC 10
#define T 1024
#define NPER 256
#define DH 32
#define D4 1024

using bf16x8 = __attribute__((ext_vector_type(8))) __bf16;
using bf16x4 = __attribute__((ext_vector_type(4))) __bf16;
using f32x4  = __attribute__((ext_vector_type(4))) float;

#define MFMA16(a, b, c) __builtin_amdgcn_mfma_f32_16x16x32_bf16((a), (b), (c), 0, 0, 0)

// ---------------- single cast kernel for all 6 weight tensors ----------------
__global__ void cast6(const float* __restrict__ s0, const float* __restrict__ s1,
                      const float* __restrict__ s2, const float* __restrict__ s3,
                      const float* __restrict__ s4, const float* __restrict__ s5,
                      __bf16* __restrict__ d0, __bf16* __restrict__ d1,
                      __bf16* __restrict__ d2, __bf16* __restrict__ d3,
                      __bf16* __restrict__ d4, __bf16* __restrict__ d5) {
    const long A4 = (long)LYR * D * D / 4;       // 131072 float4s per attn weight
    const long W4 = (long)LYR * D4 * D / 4;      // 524288 float4s per mlp weight
    long i = (long)blockIdx.x * 256 + threadIdx.x;
    const float* s; __bf16* d; long off;
    if (i < 4 * A4) {
        int w = (int)(i / A4); off = i - (long)w * A4;
        s = w == 0 ? s0 : w == 1 ? s1 : w == 2 ? s2 : s3;
        d = w == 0 ? d0 : w == 1 ? d1 : w == 2 ? d2 : d3;
    } else {
        long j = i - 4 * A4;
        int w = (int)(j / W4); off = j - (long)w * W4;
        s = w ? s5 : s4; d = w ? d5 : d4;
    }
    float4 v = ((const float4*)s)[off];
    bf16x4 o;
    o[0] = (__bf16)v.x; o[1] = (__bf16)v.y; o[2] = (__bf16)v.z; o[3] = (__bf16)v.w;
    ((bf16x4*)d)[off] = o;
}

// ---------------- patch embed + pos emb (fp32, exact: feeds discrete routing) ----------------
__global__ void patch_embed(const float* __restrict__ x, const float* __restrict__ pw,
                            const float* __restrict__ pb, const float* __restrict__ pos,
                            float* __restrict__ tok) {
    int t = blockIdx.x, b = blockIdx.y, d = threadIdx.x;
    __shared__ float sx[48];
    int ph = t >> 5, pwc = t & 31;
    if (d < 48) {
        int c = d >> 4, ij = d & 15, i = ij >> 2, j = ij & 3;
        sx[d] = x[(((long)b * 3 + c) * IMG + (ph * 4 + i)) * IMG + (pwc * 4 + j)];
    }
    __syncthreads();
    float acc = pb[d];
    #pragma unroll
    for (int kk = 0; kk < 48; ++kk) acc += sx[kk] * pw[d * 48 + kk];
    tok[((long)b * T + t) * D + d] = acc + pos[(long)t * D + d];
}

// ---------------- router softmax (fp32, exact — unchanged summation order) ----------------
__global__ void router(const float* __restrict__ tok, const float* __restrict__ rw,
                       const float* __restrict__ rb, float* __restrict__ rawp) {
    int row = blockIdx.x;
    int lane = threadIdx.x;
    const float* tr = tok + (long)row * D;
    float a0 = 0.f, a1 = 0.f, a2 = 0.f, a3 = 0.f;
    for (int c = lane; c < D; c += 64) {
        float xv = tr[c];
        a0 += xv * rw[0 * D + c];
        a1 += xv * rw[1 * D + c];
        a2 += xv * rw[2 * D + c];
        a3 += xv * rw[3 * D + c];
    }
    for (int off = 32; off; off >>= 1) {
        a0 += __shfl_down(a0, off);
        a1 += __shfl_down(a1, off);
        a2 += __shfl_down(a2, off);
        a3 += __shfl_down(a3, off);
    }
    if (lane == 0) {
        float l0 = a0 + rb[0], l1 = a1 + rb[1], l2 = a2 + rb[2], l3 = a3 + rb[3];
        float mx = fmaxf(fmaxf(l0, l1), fmaxf(l2, l3));
        float e0 = __expf(l0 - mx), e1 = __expf(l1 - mx), e2 = __expf(l2 - mx), e3 = __expf(l3 - mx);
        float inv = 1.0f / (e0 + e1 + e2 + e3);
        rawp[(long)row * 4 + 0] = e0 * inv;
        rawp[(long)row * 4 + 1] = e1 * inv;
        rawp[(long)row * 4 + 2] = e2 * inv;
        rawp[(long)row * 4 + 3] = e3 * inv;
    }
}

// ---------------- greedy routing via MSB-first radix select (partition-exact) ----------------
// Top-256 per expert over unassigned tokens; ties at threshold by lowest index (= top_k's
// stable order). Output order within an expert block is index-ascending (deterministic);
// downstream math is permutation-invariant within a block.
__global__ __launch_bounds__(1024) void route_topk(const float* __restrict__ rawp,
                                                   int* __restrict__ perm,
                                                   float* __restrict__ rpsel) {
    int b = blockIdx.x, tid = threadIdx.x;
    int lane = tid & 63, wv = tid >> 6;
    __shared__ unsigned hist[256];
    __shared__ unsigned long long ball[16];
    __shared__ int sb_bin, sb_rem;
    bool assigned = false;
    for (int e = 0; e < E; ++e) {
        float v = rawp[((long)b * T + tid) * E + e];
        unsigned key = assigned ? 0u : __float_as_uint(v);  // probs > 0 -> key 0 never selected
        unsigned prefix = 0;
        int rem = NPER;
        #pragma unroll
        for (int pass = 3; pass >= 0; --pass) {
            int shift = pass * 8;
            if (tid < 256) hist[tid] = 0;
            __syncthreads();
            bool active = (pass == 3) || ((key >> (shift + 8)) == prefix);
            if (active) atomicAdd(&hist[(key >> shift) & 255], 1u);
            __syncthreads();
            if (tid < 64) {   // wave-0 suffix-scan over 256 bins (4 per lane)
                unsigned c[4], psum = 0;
                #pragma unroll
                for (int u = 0; u < 4; ++u) { c[u] = hist[tid * 4 + u]; psum += c[u]; }
                unsigned suf = psum;
                #pragma unroll
                for (int off = 1; off < 64; off <<= 1) {
                    unsigned o = __shfl_down(suf, off);
                    if (tid + off < 64) suf += o;
                }
                unsigned El = suf - psum;          // count in bins above this lane's group
                if (El < (unsigned)rem && (unsigned)rem <= suf) {
                    unsigned cab = El;
                    #pragma unroll
                    for (int u = 3; u >= 0; --u) {
                        if ((unsigned)rem > cab && (unsigned)rem <= cab + c[u]) {
                            sb_bin = tid * 4 + u;
                            sb_rem = (int)((unsigned)rem - cab);
                        }
                        cab += c[u];
                    }
                }
            }
            __syncthreads();
            prefix = (prefix << 8) | (unsigned)sb_bin;
            rem = sb_rem;
        }
        unsigned t = prefix;                        // exact threshold key
        bool is_tie = (!assigned) && (key == t);
        unsigned long long mbt = __ballot(is_tie);
        if (lane == 0) ball[wv] = mbt;
        __syncthreads();
        int tierank = 0;
        for (int w2 = 0; w2 < wv; ++w2) tierank += __popcll(ball[w2]);
        tierank += __popcll(mbt & ((1ULL << lane) - 1));
        bool sel = (!assigned) && ((key > t) || (is_tie && tierank < rem));
        __syncthreads();
        unsigned long long mbs = __ballot(sel);
        if (lane == 0) ball[wv] = mbs;
        __syncthreads();
        int rank = 0;
        for (int w2 = 0; w2 < wv; ++w2) rank += __popcll(ball[w2]);
        rank += __popcll(mbs & ((1ULL << lane) - 1));
        if (sel) {
            perm[(long)b * T + e * NPER + rank] = tid;
            rpsel[(long)b * T + e * NPER + rank] = v;
            assigned = true;
        }
        __syncthreads();
    }
}

// ---------------- gather tokens into routed order (fp32) ----------------
__global__ void gather_tokens(const float* __restrict__ tok, const int* __restrict__ perm,
                              float* __restrict__ xs) {
    int slot = blockIdx.x, b = blockIdx.y, d = threadIdx.x;
    int src = perm[(long)b * T + slot];
    xs[((long)b * T + slot) * D + d] = tok[((long)b * T + src) * D + d];
}

// ---------------- LN of 32 rows into padded LDS (16 lanes per row, shuffle reduce) --------
__device__ __forceinline__ void ln_rows32(const float* __restrict__ src,
                                          const float* __restrict__ g,
                                          const float* __restrict__ bta,
                                          __bf16 (*slds)[264], int tid) {
    int sub = tid & 15, rowh = tid >> 4;
    int col0 = sub * 16;
    float gv[16], bv[16];
    #pragma unroll
    for (int u = 0; u < 4; ++u) {
        float4 gg = *(const float4*)&g[col0 + 4 * u];
        float4 bb = *(const float4*)&bta[col0 + 4 * u];
        gv[4*u] = gg.x; gv[4*u+1] = gg.y; gv[4*u+2] = gg.z; gv[4*u+3] = gg.w;
        bv[4*u] = bb.x; bv[4*u+1] = bb.y; bv[4*u+2] = bb.z; bv[4*u+3] = bb.w;
    }
    #pragma unroll
    for (int half = 0; half < 2; ++half) {
        int r = rowh + half * 16;
        const float* rp = src + (long)r * D + col0;
        float v[16];
        #pragma unroll
        for (int u = 0; u < 4; ++u) {
            float4 vv = *(const float4*)&rp[4 * u];
            v[4*u] = vv.x; v[4*u+1] = vv.y; v[4*u+2] = vv.z; v[4*u+3] = vv.w;
        }
        float s = 0.f;
        #pragma unroll
        for (int u = 0; u < 16; ++u) s += v[u];
        #pragma unroll
        for (int mk = 1; mk < 16; mk <<= 1) s += __shfl_xor(s, mk);
        float mu = s * (1.0f / D);
        float s2 = 0.f;
        #pragma unroll
        for (int u = 0; u < 16; ++u) { v[u] -= mu; s2 += v[u] * v[u]; }
        #pragma unroll
        for (int mk = 1; mk < 16; mk <<= 1) s2 += __shfl_xor(s2, mk);
        float rstd = rsqrtf(s2 * (1.0f / D) + 1e-5f);
        bf16x8 o0, o1;
        #pragma unroll
        for (int u = 0; u < 8; ++u) o0[u] = (__bf16)(v[u] * rstd * gv[u] + bv[u]);
        #pragma unroll
        for (int u = 0; u < 8; ++u) o1[u] = (__bf16)(v[8+u] * rstd * gv[8+u] + bv[8+u]);
        *(bf16x8*)&slds[r][col0]     = o0;
        *(bf16x8*)&slds[r][col0 + 8] = o1;
    }
}

// ---------------- MFMA GEMM core: wave computes 32x64 tile, K-loop step 32 ----------------
__device__ __forceinline__ void gemm_tile(
    const __bf16* __restrict__ A, int lda,
    const __bf16* __restrict__ W, int ldb,
    int K, int lane, f32x4 acc[2][4])
{
    int lr = lane & 15, lk = (lane >> 4) * 8;
    const __bf16* a0 = A + (long)lr * lda + lk;
    const __bf16* a1 = a0 + 16 * lda;
    const __bf16* b0 = W + (long)lr * ldb + lk;
    const __bf16* b1 = b0 + 16 * ldb;
    const __bf16* b2 = b0 + 32 * ldb;
    const __bf16* b3 = b0 + 48 * ldb;
    #pragma unroll 2
    for (int k = 0; k < K; k += 32) {
        bf16x8 av0 = *(const bf16x8*)(a0 + k);
        bf16x8 av1 = *(const bf16x8*)(a1 + k);
        bf16x8 bv0 = *(const bf16x8*)(b0 + k);
        bf16x8 bv1 = *(const bf16x8*)(b1 + k);
        bf16x8 bv2 = *(const bf16x8*)(b2 + k);
        bf16x8 bv3 = *(const bf16x8*)(b3 + k);
        acc[0][0] = MFMA16(av0, bv0, acc[0][0]);
        acc[0][1] = MFMA16(av0, bv1, acc[0][1]);
        acc[0][2] = MFMA16(av0, bv2, acc[0][2]);
        acc[0][3] = MFMA16(av0, bv3, acc[0][3]);
        acc[1][0] = MFMA16(av1, bv0, acc[1][0]);
        acc[1][1] = MFMA16(av1, bv1, acc[1][1]);
        acc[1][2] = MFMA16(av1, bv2, acc[1][2]);
        acc[1][3] = MFMA16(av1, bv3, acc[1][3]);
    }
}

// ---------------- fused LN1 + QKV projection (block: 32 rows x 256 cols of one of q/k/v) ----
__global__ __launch_bounds__(256) void qkv_ln_gemm(
    const float* __restrict__ xs,
    const __bf16* __restrict__ qwb, const __bf16* __restrict__ kwb, const __bf16* __restrict__ vwb,
    const float* __restrict__ qb, const float* __restrict__ kb, const float* __restrict__ vb,
    const float* __restrict__ g, const float* __restrict__ bta,
    __bf16* __restrict__ Qb, __bf16* __restrict__ Kb, __bf16* __restrict__ Vt)
{
    int tid = threadIdx.x, lane = tid & 63, wid = tid >> 6;
    int tile = blockIdx.x, which = blockIdx.y, b = blockIdx.z;
    int row0 = tile * 32;
    int m = D >> (row0 >> 8);
    __shared__ __bf16 slds[32][264];
    ln_rows32(xs + ((long)b * T + row0) * D, g, bta, slds, tid);
    __syncthreads();
    const __bf16* W = which == 0 ? qwb : which == 1 ? kwb : vwb;
    const float* bias = which == 0 ? qb : which == 1 ? kb : vb;
    int ncol0 = wid * 64;
    const f32x4 vz = {0.f, 0.f, 0.f, 0.f};
    f32x4 acc[2][4];
    #pragma unroll
    for (int i = 0; i < 2; ++i) { acc[i][0]=vz; acc[i][1]=vz; acc[i][2]=vz; acc[i][3]=vz; }
    gemm_tile(&slds[0][0], 264, W + (long)ncol0 * D, D, m, lane, acc);
    int lr = lane & 15, rg = (lane >> 4) * 4;
    #pragma unroll
    for (int i = 0; i < 2; ++i) {
        int row = row0 + i * 16 + rg;
        #pragma unroll
        for (int j = 0; j < 4; ++j) {
            int n = ncol0 + j * 16 + lr;
            float bvs = bias[n];
            if (which == 2) {
                bf16x4 pk;
                #pragma unroll
                for (int r = 0; r < 4; ++r) pk[r] = (__bf16)(acc[i][j][r] + bvs);
                *(bf16x4*)&Vt[((long)b * D + n) * T + row] = pk;
            } else if (which == 0) {
                #pragma unroll
                for (int r = 0; r < 4; ++r)   // fold attention scale 2^-4 into Q
                    Qb[((long)b * T + row + r) * D + n] = (__bf16)((acc[i][j][r] + bvs) * 0.0625f);
            } else {
                #pragma unroll
                for (int r = 0; r < 4; ++r)
                    Kb[((long)b * T + row + r) * D + n] = (__bf16)(acc[i][j][r] + bvs);
            }
        }
    }
}

// ---------------- attention: swapped-QK^T MFMA flash, 32 q/wave, KVBLK=64, no barriers ------
__global__ __launch_bounds__(256) void attn_mfma(
    const __bf16* __restrict__ Qb, const __bf16* __restrict__ Kb,
    const __bf16* __restrict__ Vt, __bf16* __restrict__ aob)
{
    int bid = blockIdx.x;
    int bh = (bid & 7) * 8 + ((bid >> 3) & 7);
    int qt = bid >> 6;
    int b = bh >> 3, h = bh & 7;
    int lane = threadIdx.x & 63, wave = threadIdx.x >> 6;
    int lr = lane & 15, g = lane >> 4;
    int q0 = qt * 128 + wave * 32;
    __shared__ __bf16 plds[4][32][72];
    const f32x4 vz = {0.f, 0.f, 0.f, 0.f};
    bf16x8 qf[2];
    qf[0] = *(const bf16x8*)&Qb[((long)b * T + q0 + lr) * D + h * DH + g * 8];
    qf[1] = *(const bf16x8*)&Qb[((long)b * T + q0 + 16 + lr) * D + h * DH + g * 8];
    f32x4 acc[2][2] = {{vz, vz}, {vz, vz}};
    float ls[2] = {0.f, 0.f};
    const __bf16* kbase = Kb + (long)b * T * D + h * DH + g * 8;
    const __bf16* vbase = Vt + ((long)b * D + h * DH) * T;
    for (int kc = 0; kc < T; kc += 64) {
        bf16x8 kf[4];
        #pragma unroll
        for (int j = 0; j < 4; ++j)
            kf[j] = *(const bf16x8*)(kbase + (long)(kc + 16 * j + lr) * D);
        bf16x8 vf[2][2];
        #pragma unroll
        for (int w = 0; w < 2; ++w)
            #pragma unroll
            for (int df = 0; df < 2; ++df)
                vf[w][df] = *(const bf16x8*)(vbase + (long)(df * 16 + lr) * T + kc + 32 * w + 8 * g);
        #pragma unroll
        for (int qi = 0; qi < 2; ++qi) {
            #pragma unroll
            for (int j = 0; j < 4; ++j) {
                f32x4 s = MFMA16(kf[j], qf[qi], vz);
                float p0 = __expf(s[0]), p1 = __expf(s[1]);
                float p2 = __expf(s[2]), p3 = __expf(s[3]);
                ls[qi] += (p0 + p1) + (p2 + p3);
                bf16x4 pk;
                pk[0] = (__bf16)p0; pk[1] = (__bf16)p1;
                pk[2] = (__bf16)p2; pk[3] = (__bf16)p3;
                *(bf16x4*)&plds[wave][qi * 16 + lr][16 * j + 4 * g] = pk;
            }
        }
        #pragma unroll
        for (int qi = 0; qi < 2; ++qi) {
            #pragma unroll
            for (int w = 0; w < 2; ++w) {
                bf16x8 pa = *(const bf16x8*)&plds[wave][qi * 16 + lr][32 * w + 8 * g];
                acc[qi][0] = MFMA16(pa, vf[w][0], acc[qi][0]);
                acc[qi][1] = MFMA16(pa, vf[w][1], acc[qi][1]);
            }
        }
    }
    #pragma unroll
    for (int qi = 0; qi < 2; ++qi) {
        ls[qi] += __shfl_xor(ls[qi], 16);
        ls[qi] += __shfl_xor(ls[qi], 32);
        float inv = 1.0f / ls[qi];
        #pragma unroll
        for (int r = 0; r < 4; ++r) {
            float invr = __shfl(inv, 4 * g + r);
            long obase = ((long)b * T + q0 + qi * 16 + 4 * g + r) * D + h * DH;
            aob[obase + lr]      = (__bf16)(acc[qi][0][r] * invr);
            aob[obase + 16 + lr] = (__bf16)(acc[qi][1][r] * invr);
        }
    }
}

#define GEMM_PROLOGUE \
    int lane = threadIdx.x & 63, wid = threadIdx.x >> 6; \
    int wm = wid >> 1, wn = wid & 1; \
    int b = blockIdx.z >> 2, e = blockIdx.z & 3; \
    int m = D >> e; \
    const f32x4 vz = {0.f, 0.f, 0.f, 0.f}; \
    f32x4 acc[2][4]; \
    _Pragma("unroll") \
    for (int i = 0; i < 2; ++i) { acc[i][0]=vz; acc[i][1]=vz; acc[i][2]=vz; acc[i][3]=vz; }

// ---------------- O projection GEMM + residual into fp32 xs ----------------
__global__ __launch_bounds__(256) void oproj_gemm(
    const __bf16* __restrict__ aob, const __bf16* __restrict__ owb,
    const float* __restrict__ ob, float* __restrict__ xs)
{
    GEMM_PROLOGUE
    if ((int)blockIdx.y * 128 >= m) return;
    int ncol0 = blockIdx.y * 128 + wn * 64;
    int row0 = e * NPER + blockIdx.x * 64 + wm * 32;
    gemm_tile(aob + ((long)b * T + row0) * D, D, owb + (long)ncol0 * D, D, m, lane, acc);
    int lr = lane & 15, rg = (lane >> 4) * 4;
    #pragma unroll
    for (int i = 0; i < 2; ++i) {
        int row = row0 + i * 16 + rg;
        #pragma unroll
        for (int j = 0; j < 4; ++j) {
            int n = ncol0 + j * 16 + lr;
            if (n < m) {
                float bv = ob[n];
                #pragma unroll
                for (int r = 0; r < 4; ++r)
                    xs[((long)b * T + row + r) * D + n] += acc[i][j][r] + bv;
            }
        }
    }
}

// ---------------- fused LN2 + MLP layer 1 GEMM + exact gelu -> bf16 inner ----------------
__global__ __launch_bounds__(256) void mlp1_ln_gemm(
    const float* __restrict__ xs, const __bf16* __restrict__ w1b,
    const float* __restrict__ b1, const float* __restrict__ g, const float* __restrict__ bta,
    __bf16* __restrict__ innerb)
{
    int tid = threadIdx.x, lane = tid & 63, wid = tid >> 6;
    int tile = blockIdx.x, fq = blockIdx.y, b = blockIdx.z;
    int row0 = tile * 32;
    int m = D >> (row0 >> 8);
    __shared__ __bf16 slds[32][264];
    ln_rows32(xs + ((long)b * T + row0) * D, g, bta, slds, tid);
    __syncthreads();
    int ncol0 = fq * 256 + wid * 64;
    const f32x4 vz = {0.f, 0.f, 0.f, 0.f};
    f32x4 acc[2][4];
    #pragma unroll
    for (int i = 0; i < 2; ++i) { acc[i][0]=vz; acc[i][1]=vz; acc[i][2]=vz; acc[i][3]=vz; }
    gemm_tile(&slds[0][0], 264, w1b + (long)ncol0 * D, D, m, lane, acc);
    int lr = lane & 15, rg = (lane >> 4) * 4;
    #pragma unroll
    for (int i = 0; i < 2; ++i) {
        int row = row0 + i * 16 + rg;
        #pragma unroll
        for (int j = 0; j < 4; ++j) {
            int f = ncol0 + j * 16 + lr;
            float bv = b1[f];
            #pragma unroll
            for (int r = 0; r < 4; ++r) {
                float xv = acc[i][j][r] + bv;
                float gl = 0.5f * xv * (1.0f + erff(xv * 0.70710678118654752f));
                innerb[((long)b * T + row + r) * D4 + f] = (__bf16)gl;
            }
        }
    }
}

// ---------------- MLP layer 2 GEMM + sf-scaled residual into fp32 xs ----------------
__global__ __launch_bounds__(256) void mlp2_gemm(
    const __bf16* __restrict__ innerb, const __bf16* __restrict__ w2b,
    const float* __restrict__ b2, const float* __restrict__ rpsel,
    const float* __restrict__ alpha, float* __restrict__ xs)
{
    GEMM_PROLOGUE
    if ((int)blockIdx.y * 128 >= m) return;
    int ncol0 = blockIdx.y * 128 + wn * 64;
    int row0 = e * NPER + blockIdx.x * 64 + wm * 32;
    gemm_tile(innerb + ((long)b * T + row0) * D4, D4, w2b + (long)ncol0 * D4, D4, D4, lane, acc);
    int lr = lane & 15, rg = (lane >> 4) * 4;
    float a0 = alpha[0];
    #pragma unroll
    for (int i = 0; i < 2; ++i) {
        int row = row0 + i * 16 + rg;
        float sf[4];
        #pragma unroll
        for (int r = 0; r < 4; ++r) sf[r] = a0 * rpsel[(long)b * T + row + r] + 1.0f;
        #pragma unroll
        for (int j = 0; j < 4; ++j) {
            int n = ncol0 + j * 16 + lr;
            if (n < m) {
                float bv = b2[n];
                #pragma unroll
                for (int r = 0; r < 4; ++r)
                    xs[((long)b * T + row + r) * D + n] += sf[r] * (acc[i][j][r] + bv);
            }
        }
    }
}

// ---------------- mean pool (2-stage, deterministic) + head ----------------
__global__ void head_partial(const float* __restrict__ xs, float* __restrict__ part) {
    int c = blockIdx.x, b = blockIdx.y, d = threadIdx.x;
    const float* p = xs + ((long)b * T + c * 128) * D + d;
    float s = 0.f;
    #pragma unroll 8
    for (int i = 0; i < 128; ++i) s += p[(long)i * D];
    part[((long)b * 8 + c) * D + d] = s;
}

__global__ void head_final(const float* __restrict__ part, const float* __restrict__ hw,
                           const float* __restrict__ hb, float* __restrict__ out) {
    int b = blockIdx.x, d = threadIdx.x;
    __shared__ float smean[D];
    float s = 0.f;
    #pragma unroll
    for (int c = 0; c < 8; ++c) s += part[((long)b * 8 + c) * D + d];
    smean[d] = s * (1.0f / T);
    __syncthreads();
    if (d < NC) {
        float acc = hb[d];
        for (int c = 0; c < D; ++c) acc += smean[c] * hw[d * D + c];
        out[b * NC + d] = acc;
    }
}

extern "C" void kernel_launch(void* const* d_in, const int* in_sizes, int n_in,
                              void* d_out, int out_size, void* d_ws, size_t ws_size,
                              hipStream_t stream) {
    const float* x      = (const float*)d_in[0];
    const float* patchw = (const float*)d_in[1];
    const float* patchb = (const float*)d_in[2];
    const float* pos    = (const float*)d_in[3];
    const float* rw     = (const float*)d_in[4];
    const float* rb     = (const float*)d_in[5];
    const float* ln1g   = (const float*)d_in[6];
    const float* ln1b   = (const float*)d_in[7];
    const float* qw     = (const float*)d_in[8];
    const float* qbi    = (const float*)d_in[9];
    const float* kw     = (const float*)d_in[10];
    const float* kbi    = (const float*)d_in[11];
    const float* vw     = (const float*)d_in[12];
    const float* vbi    = (const float*)d_in[13];
    const float* ow     = (const float*)d_in[14];
    const float* obi    = (const float*)d_in[15];
    const float* ln2g   = (const float*)d_in[16];
    const float* ln2b   = (const float*)d_in[17];
    const float* l1w    = (const float*)d_in[18];
    const float* l1b    = (const float*)d_in[19];
    const float* l2w    = (const float*)d_in[20];
    const float* l2b    = (const float*)d_in[21];
    const float* hw     = (const float*)d_in[22];
    const float* hb     = (const float*)d_in[23];
    const float* alpha  = (const float*)d_in[24];

    char* p = (char*)d_ws;
    auto alloc = [&](size_t bytes) { void* r = (void*)p; p += (bytes + 255) & ~(size_t)255; return r; };
    const long NTD = (long)BB * T * D;

    float*  tok    = (float*)alloc(NTD * 4);
    float*  xs     = (float*)alloc(NTD * 4);
    float*  rawp   = (float*)alloc((long)BB * T * E * 4);
    float*  rpsel  = (float*)alloc((long)BB * T * 4);
    int*    perm   = (int*)alloc((long)BB * T * 4);
    float*  part   = (float*)alloc((long)BB * 8 * D * 4);
    __bf16* Qb     = (__bf16*)alloc(NTD * 2);
    __bf16* Kb     = (__bf16*)alloc(NTD * 2);
    __bf16* Vt     = (__bf16*)alloc(NTD * 2);
    __bf16* aob    = (__bf16*)alloc(NTD * 2);
    __bf16* innerb = (__bf16*)alloc((long)BB * T * D4 * 2);
    __bf16* qwb    = (__bf16*)alloc((long)LYR * D * D * 2);
    __bf16* kwb    = (__bf16*)alloc((long)LYR * D * D * 2);
    __bf16* vwb    = (__bf16*)alloc((long)LYR * D * D * 2);
    __bf16* owb    = (__bf16*)alloc((long)LYR * D * D * 2);
    __bf16* w1b    = (__bf16*)alloc((long)LYR * D4 * D * 2);
    __bf16* w2b    = (__bf16*)alloc((long)LYR * D * D4 * 2);

    cast6<<<6144, 256, 0, stream>>>(qw, kw, vw, ow, l1w, l2w, qwb, kwb, vwb, owb, w1b, w2b);

    patch_embed<<<dim3(T, BB), D, 0, stream>>>(x, patchw, patchb, pos, tok);
    router<<<BB * T, 64, 0, stream>>>(tok, rw, rb, rawp);
    route_topk<<<BB, 1024, 0, stream>>>(rawp, perm, rpsel);
    gather_tokens<<<dim3(T, BB), D, 0, stream>>>(tok, perm, xs);

    for (int l = 0; l < LYR; ++l) {
        qkv_ln_gemm<<<dim3(32, 3, BB), 256, 0, stream>>>(
            xs, qwb + (long)l * D * D, kwb + (long)l * D * D, vwb + (long)l * D * D,
            qbi + l * D, kbi + l * D, vbi + l * D,
            ln1g + l * D, ln1b + l * D, Qb, Kb, Vt);
        attn_mfma<<<dim3(512), 256, 0, stream>>>(Qb, Kb, Vt, aob);
        oproj_gemm<<<dim3(4, 2, BB * E), 256, 0, stream>>>(
            aob, owb + (long)l * D * D, obi + l * D, xs);
        mlp1_ln_gemm<<<dim3(32, 4, BB), 256, 0, stream>>>(
            xs, w1b + (long)l * D4 * D, l1b + (long)l * D4,
            ln2g + l * D, ln2b + l * D, innerb);
        mlp2_gemm<<<dim3(4, 2, BB * E), 256, 0, stream>>>(
            innerb, w2b + (long)l * D * D4, l2b + l * D, rpsel, alpha, xs);
    }

    head_partial<<<dim3(8, BB), 256, 0, stream>>>(xs, part);
    head_final<<<BB, D, 0, stream>>>(part, hw, hb, (float*)d_out);
}